// Round 3
// baseline (478.377 us; speedup 1.0000x reference)
//
#include <hip/hip_runtime.h>
#include <hip/hip_bf16.h>

// Problem constants
// B=32, N=64, D=30, ND=64, F0=64, H1=128, H2=64, H3=32, L=8, SINK_K=10
// LAMDA = {0.01,0.1,0.5,1.0,3.0,5.0,10.0,20.0}, P0=0.5, EPS=1e-6

__device__ __constant__ float c_LAM[8] = {0.01f, 0.1f, 0.5f, 1.0f, 3.0f, 5.0f, 10.0f, 20.0f};

// ---------------- workspace layout (float offsets) ----------------
constexpr int OFF_XE   = 0;         // 32*64*32 = 65536
constexpr int OFF_DE   = 65536;     // 30*64*32 = 61440
constexpr int OFF_DS   = 126976;    // 30*64*32 = 61440
constexpr int OFF_X2   = 188416;    // 2048
constexpr int OFF_Y2   = 190464;    // 1920
constexpr int OFF_Z    = 192384;    // 32
constexpr int OFF_C0   = 192416;    // 16
constexpr int OFF_KL   = 192432;    // 48
constexpr int OFF_GALL = 192480;    // 8*32*960 = 245760
constexpr int OFF_WBUF = 438272;    // 7680*4096 = 31457280

// wave-uniform broadcast of another lane's value (lane must be compile-time const)
__device__ __forceinline__ float lane_bcast(float v, int lane) {
  return __int_as_float(__builtin_amdgcn_readlane(__float_as_int(v), lane));
}

// =====================================================================
// GCN encoder: one block per graph (blocks 0..31 = x-encoder, 32..61 = dict)
// =====================================================================
template <int K, int J>
__device__ __forceinline__ void mm64(const float* __restrict__ A, int lda,
                                     const float* __restrict__ W,
                                     float* __restrict__ C,
                                     const float* __restrict__ bias,
                                     bool do_relu, int t) {
  constexpr int JT = J >> 2;        // float4 tiles per row
  constexpr int TILES = 16 * JT;    // 16 i-tiles (64 rows / 4)
  for (int task = t; task < TILES; task += 256) {
    int i4 = task / JT;
    int j4 = task - i4 * JT;
    const float* a0 = A + (i4 * 4 + 0) * lda;
    const float* a1 = a0 + lda;
    const float* a2 = a1 + lda;
    const float* a3 = a2 + lda;
    float acc[4][4];
#pragma unroll
    for (int r = 0; r < 4; ++r)
#pragma unroll
      for (int c = 0; c < 4; ++c) acc[r][c] = 0.0f;
    const float* wp = W + j4 * 4;
#pragma unroll 8
    for (int k = 0; k < K; ++k) {
      float4 w = *(const float4*)(wp + k * J);
      float v0 = a0[k], v1 = a1[k], v2 = a2[k], v3 = a3[k];
      acc[0][0] += v0 * w.x; acc[0][1] += v0 * w.y; acc[0][2] += v0 * w.z; acc[0][3] += v0 * w.w;
      acc[1][0] += v1 * w.x; acc[1][1] += v1 * w.y; acc[1][2] += v1 * w.z; acc[1][3] += v1 * w.w;
      acc[2][0] += v2 * w.x; acc[2][1] += v2 * w.y; acc[2][2] += v2 * w.z; acc[2][3] += v2 * w.w;
      acc[3][0] += v3 * w.x; acc[3][1] += v3 * w.y; acc[3][2] += v3 * w.z; acc[3][3] += v3 * w.w;
    }
    float4 bv = make_float4(0.f, 0.f, 0.f, 0.f);
    if (bias) bv = *(const float4*)(bias + j4 * 4);
#pragma unroll
    for (int r = 0; r < 4; ++r) {
      float o0 = acc[r][0] + bv.x, o1 = acc[r][1] + bv.y;
      float o2 = acc[r][2] + bv.z, o3 = acc[r][3] + bv.w;
      if (do_relu) {
        o0 = fmaxf(o0, 0.f); o1 = fmaxf(o1, 0.f);
        o2 = fmaxf(o2, 0.f); o3 = fmaxf(o3, 0.f);
      }
      float4 st = make_float4(o0, o1, o2, o3);
      *(float4*)(C + (i4 * 4 + r) * J + j4 * 4) = st;
    }
  }
}

__global__ __launch_bounds__(256) void gcn_kernel(
    const float* __restrict__ x, const float* __restrict__ adj,
    const float* __restrict__ eW1, const float* __restrict__ eb1,
    const float* __restrict__ eW2, const float* __restrict__ eb2,
    const float* __restrict__ eW3, const float* __restrict__ eb3,
    const float* __restrict__ dx, const float* __restrict__ dadj,
    const float* __restrict__ dW1, const float* __restrict__ db1,
    const float* __restrict__ dW2, const float* __restrict__ db2,
    const float* __restrict__ dW3, const float* __restrict__ db3,
    float* __restrict__ xe, float* __restrict__ de,
    float* __restrict__ x2b) {
  __shared__ __align__(16) float C0[64 * 128];
  __shared__ __align__(16) float C1[64 * 128];
  int t = threadIdx.x;
  const float *src, *ad, *W1, *b1, *W2, *b2, *W3, *b3;
  float* outp;
  bool is_x = (blockIdx.x < 32);
  int g;
  if (is_x) {
    g = blockIdx.x;
    src = x + g * 4096; ad = adj + g * 4096;
    W1 = eW1; b1 = eb1; W2 = eW2; b2 = eb2; W3 = eW3; b3 = eb3;
    outp = xe + g * 2048;
  } else {
    g = blockIdx.x - 32;
    src = dx + g * 4096; ad = dadj + g * 4096;
    W1 = dW1; b1 = db1; W2 = dW2; b2 = db2; W3 = dW3; b3 = db3;
    outp = de + g * 2048;
  }
  mm64<64, 128>(src, 64, W1, C1, nullptr, false, t);
  __syncthreads();
  mm64<64, 128>(ad, 64, C1, C0, b1, true, t);
  __syncthreads();
  mm64<128, 64>(C0, 128, W2, C1, nullptr, false, t);
  __syncthreads();
  mm64<64, 64>(ad, 64, C1, C0, b2, true, t);
  __syncthreads();
  mm64<64, 32>(C0, 64, W3, C1, nullptr, false, t);
  __syncthreads();
  mm64<64, 32>(ad, 64, C1, outp, b3, false, t);
  __syncthreads();
  // fused x2 epilogue for x-encoder blocks
  if (is_x && t < 64) {
    const float* r = outp + t * 32;
    float s = 0.f;
#pragma unroll
    for (int f = 0; f < 32; ++f) s += r[f] * r[f];
    x2b[g * 64 + t] = s;
  }
}

// =====================================================================
__global__ __launch_bounds__(256) void z_kernel(
    const float* __restrict__ xe, const float* __restrict__ mlp_w,
    const float* __restrict__ mlp_b, const float* __restrict__ mlp2_w,
    const float* __restrict__ mlp2_b, float* __restrict__ z,
    float* __restrict__ c0) {
  __shared__ float yb[32 * 33];
  int t = threadIdx.x;
  for (int idx = t; idx < 1024; idx += 256) {
    int b = idx >> 5, f = idx & 31;
    float s = 0.f, sb = 0.f;
    for (int n = 0; n < 64; ++n) {
      float v = xe[b * 2048 + n * 32 + f];
      s += v * v;
      sb += v * mlp_w[n];
    }
    yb[b * 33 + f] = sb / (sqrtf(s) + 1e-12f);
  }
  __syncthreads();
  if (t < 32) {
    float zz = 0.f;
    for (int b = 0; b < 32; ++b) zz += yb[b * 33 + t] * mlp2_w[b];
    z[t] = zz;
    if (t == 0) {
      float sm2 = 0.f;
      for (int b = 0; b < 32; ++b) sm2 += mlp2_w[b];
      c0[0] = mlp_b[0] * sm2 + mlp2_b[0];
    }
  }
}

// =====================================================================
// JAX threefry2x32, key = (0, 42)
// =====================================================================
__device__ __forceinline__ unsigned rotl32(unsigned v, int s) {
  return (v << s) | (v >> (32 - s));
}
__device__ __forceinline__ void threefry42(unsigned x0, unsigned x1,
                                           unsigned& o0, unsigned& o1) {
  const unsigned ks0 = 0u, ks1 = 42u, ks2 = 0x1BD11BDAu ^ 0u ^ 42u;
  unsigned ks[3] = {ks0, ks1, ks2};
  x0 += ks[0];
  x1 += ks[1];
  const int R[2][4] = {{13, 15, 26, 6}, {17, 29, 16, 24}};
#pragma unroll
  for (int r = 0; r < 5; ++r) {
    const int* rr = R[r & 1];
#pragma unroll
    for (int i = 0; i < 4; ++i) {
      x0 += x1;
      x1 = rotl32(x1, rr[i]);
      x1 ^= x0;
    }
    x0 += ks[(r + 1) % 3];
    x1 += ks[(r + 2) % 3] + (unsigned)(r + 1);
  }
  o0 = x0;
  o1 = x1;
}

// =====================================================================
__global__ __launch_bounds__(64) void attn_kernel(
    const float* __restrict__ de, const float* __restrict__ z,
    const float* __restrict__ c0, float* __restrict__ dsamp,
    float* __restrict__ y2, float* __restrict__ klpart) {
  int d = blockIdx.x, m = threadIdx.x;
  __shared__ float dn[32];
  if (m < 32) {
    float s = 0.f;
    for (int n = 0; n < 64; ++n) {
      float v = de[d * 2048 + n * 32 + m];
      s += v * v;
    }
    dn[m] = sqrtf(s) + 1e-12f;
  }
  __syncthreads();
  const float* row = de + d * 2048 + m * 32;
  float logit = c0[0], s2 = 0.f;
#pragma unroll 8
  for (int f = 0; f < 32; ++f) {
    float v = row[f];
    logit += (v / dn[f]) * z[f];
    s2 += v * v;
  }
  float attn = 1.0f / (1.0f + expf(-logit));
  int e = d * 64 + m;
  unsigned o0, o1, bits;
  if (e < 960) {
    threefry42((unsigned)e, (unsigned)(960 + e), o0, o1);
    bits = o0;
  } else {
    threefry42((unsigned)(e - 960), (unsigned)e, o0, o1);
    bits = o1;
  }
  float u = __uint_as_float((bits >> 9) | 0x3f800000u) - 1.0f;
  u = fmaxf(u, 0.0f);
  float bern = (u < attn) ? 1.0f : 0.0f;
  float* dr = dsamp + d * 2048 + m * 32;
#pragma unroll 8
  for (int f = 0; f < 32; ++f) dr[f] = bern * row[f];
  y2[e] = bern * s2;
  float klt = attn * logf(2.0f * attn) + (1.0f - attn) * logf(2.0f * (1.0f - attn));
#pragma unroll
  for (int off = 32; off > 0; off >>= 1) klt += __shfl_down(klt, off, 64);
  if (m == 0) klpart[d] = klt;
}

// =====================================================================
// Sinkhorn: one block per (b,d); one WAVE per lambda (2 reps of 4 waves).
// K rows+cols live in registers; matvecs are readlane-broadcast FMAs.
// Zero barriers inside the Sinkhorn iteration.
// =====================================================================
__global__ __launch_bounds__(256) void sink_kernel(
    const float* __restrict__ xe, const float* __restrict__ ds,
    const float* __restrict__ x2g, const float* __restrict__ y2g,
    const int* __restrict__ num_node, const int* __restrict__ dict_nnode,
    float* __restrict__ Wbuf) {
  __shared__ __align__(16) float XEs[64 * 33];
  __shared__ __align__(16) float DSs[64 * 33];
  __shared__ __align__(16) float Ms[64 * 65];
  __shared__ float w1s[64], w2s[64], x2s[64], y2s[64];
  __shared__ float uiL[8 * 64], viL[8 * 64], rminL[8 * 64], rinvL[8 * 64];

  int t = threadIdx.x;
  int b = blockIdx.x / 30;
  int d = blockIdx.x - b * 30;

  {
    const float* xsrc = xe + b * 2048;
    const float* dsrc = ds + d * 2048;
    for (int i = t; i < 2048; i += 256) {
      int r = i >> 5, c = i & 31;
      XEs[r * 33 + c] = xsrc[i];
      DSs[r * 33 + c] = dsrc[i];
    }
  }
  if (t < 64) {
    int nn = num_node[b], dnn = dict_nnode[d];
    w1s[t] = (t < nn) ? 1.0f / (float)nn : 0.0f;
    w2s[t] = (t < dnn) ? 1.0f / (float)dnn : 0.0f;
    x2s[t] = x2g[b * 64 + t];
    y2s[t] = y2g[d * 64 + t];
  }
  __syncthreads();
  // M[i][j] = x2[i] + y2[j] - 2 <xe_i, ds_j>
  for (int idx = t; idx < 4096; idx += 256) {
    int i = idx >> 6, j = idx & 63;
    const float* xr = XEs + i * 33;
    const float* dr = DSs + j * 33;
    float acc = 0.f;
#pragma unroll
    for (int f = 0; f < 32; ++f) acc += xr[f] * dr[f];
    Ms[i * 65 + j] = x2s[i] + y2s[j] - 2.0f * acc;
  }
  __syncthreads();

  const int m = t & 63;
  const int wv = t >> 6;
  float w1m = w1s[m], w2m = w2s[m];
  float rmask = (w1m > 0.f) ? 1.f : 0.f;
  float cmask = (w2m > 0.f) ? 1.f : 0.f;

  for (int rep = 0; rep < 2; ++rep) {
    int l = wv + rep * 4;
    float lam = c_LAM[l];
    float kr[64], kc[64];
#pragma unroll
    for (int j = 0; j < 64; ++j) {
      float e = __expf(-lam * Ms[m * 65 + j]);
      kr[j] = (w2s[j] > 0.f) ? e * rmask : 0.f;
    }
#pragma unroll
    for (int i = 0; i < 64; ++i) {
      float e = __expf(-lam * Ms[i * 65 + m]);
      kc[i] = (w1s[i] > 0.f) ? e * cmask : 0.f;
    }
    float u = 1.0f, v = 0.0f;
    for (int it = 0; it < 10; ++it) {
      float tv = 0.f;
#pragma unroll
      for (int i = 0; i < 64; ++i) tv = fmaf(kc[i], lane_bcast(u, i), tv);
      v = w2m / (tv + 1e-6f);
      float tu = 0.f;
#pragma unroll
      for (int j = 0; j < 64; ++j) tu = fmaf(kr[j], lane_bcast(v, j), tu);
      u = w1m / (tu + 1e-6f);
    }
    float mx = -3.402823466e38f, mn = 3.402823466e38f;
#pragma unroll
    for (int j = 0; j < 64; ++j) {
      float g = u * kr[j] * lane_bcast(v, j);
      mx = fmaxf(mx, g);
      mn = fminf(mn, g);
    }
    uiL[l * 64 + m] = u;
    viL[l * 64 + m] = v;
    rminL[l * 64 + m] = mn;
    rinvL[l * 64 + m] = 1.0f / (mx - mn + 1e-6f);
  }
  __syncthreads();

  // W-gen: recompute K, form Ghat*M, coalesced scalar stores
  int base = b * 30 + d;
  for (int l = 0; l < 8; ++l) {
    float lam = c_LAM[l];
    float* wrow = Wbuf + (size_t)(l * 960 + base) * 4096;
#pragma unroll
    for (int e = 0; e < 16; ++e) {
      int idx = e * 256 + t;
      int i = idx >> 6, j = idx & 63;
      float mv = Ms[i * 65 + j];
      float kvv = ((w1s[i] > 0.f) && (w2s[j] > 0.f)) ? __expf(-lam * mv) : 0.f;
      float g = uiL[l * 64 + i] * kvv * viL[l * 64 + j];
      float gh = (g - rminL[l * 64 + i]) * rinvL[l * 64 + i];
      wrow[idx] = gh * mv;
    }
  }
}

// =====================================================================
// gall(7680x32) = Wbuf(7680x4096) @ dp(4096x32)
// 960 blocks x 256 thr, 8 rows/block; coalesced float4 W loads via
// k-interleaved mapping: thread (kg=t>>3, col4=t&7), step s covers
// k = s*128 + kg*4 .. +4.
// =====================================================================
__global__ __launch_bounds__(256) void gd_gemm_kernel(
    const float* __restrict__ Wbuf, const float* __restrict__ dp,
    float* __restrict__ gall) {
  __shared__ __align__(16) float4 red[4 * 8 * 8];  // [wave][row][col4]
  int t = threadIdx.x;
  int col4 = t & 7;
  int kg = t >> 3;          // 0..31
  int wv = t >> 6;          // 0..3
  int r0 = blockIdx.x << 3; // 8 rows per block
  const float4* dp4 = (const float4*)dp;
  const float* Wb = Wbuf + (size_t)r0 * 4096;

  float4 acc[8];
#pragma unroll
  for (int r = 0; r < 8; ++r) acc[r] = make_float4(0.f, 0.f, 0.f, 0.f);

  for (int s = 0; s < 32; ++s) {
    int kbase = s * 128 + kg * 4;
    float4 dv0 = dp4[(kbase + 0) * 8 + col4];
    float4 dv1 = dp4[(kbase + 1) * 8 + col4];
    float4 dv2 = dp4[(kbase + 2) * 8 + col4];
    float4 dv3 = dp4[(kbase + 3) * 8 + col4];
#pragma unroll
    for (int r = 0; r < 8; ++r) {
      float4 w4 = *(const float4*)(Wb + r * 4096 + kbase);
      acc[r].x += w4.x * dv0.x + w4.y * dv1.x + w4.z * dv2.x + w4.w * dv3.x;
      acc[r].y += w4.x * dv0.y + w4.y * dv1.y + w4.z * dv2.y + w4.w * dv3.y;
      acc[r].z += w4.x * dv0.z + w4.y * dv1.z + w4.z * dv2.z + w4.w * dv3.z;
      acc[r].w += w4.x * dv0.w + w4.y * dv1.w + w4.z * dv2.w + w4.w * dv3.w;
    }
  }
  // reduce across kg (lane stride 8) within wave
#pragma unroll
  for (int off = 32; off >= 8; off >>= 1) {
#pragma unroll
    for (int r = 0; r < 8; ++r) {
      acc[r].x += __shfl_down(acc[r].x, off, 64);
      acc[r].y += __shfl_down(acc[r].y, off, 64);
      acc[r].z += __shfl_down(acc[r].z, off, 64);
      acc[r].w += __shfl_down(acc[r].w, off, 64);
    }
  }
  if ((t & 63) < 8) {
#pragma unroll
    for (int r = 0; r < 8; ++r) red[(wv * 8 + r) * 8 + col4] = acc[r];
  }
  __syncthreads();
  if (t < 64) {
    int r = t >> 3, c4 = t & 7;
    float4 s = red[(0 * 8 + r) * 8 + c4];
    float4 s1 = red[(1 * 8 + r) * 8 + c4];
    float4 s2 = red[(2 * 8 + r) * 8 + c4];
    float4 s3 = red[(3 * 8 + r) * 8 + c4];
    s.x += s1.x + s2.x + s3.x;
    s.y += s1.y + s2.y + s3.y;
    s.z += s1.z + s2.z + s3.z;
    s.w += s1.w + s2.w + s3.w;
    *(float4*)(gall + (size_t)(r0 + r) * 32 + c4 * 4) = s;
  }
}

// =====================================================================
__global__ __launch_bounds__(256) void final_kernel(
    const float* __restrict__ gall, const float* __restrict__ wl,
    const float* __restrict__ fc1w, const float* __restrict__ fc1b,
    const float* __restrict__ fc2w, const float* __restrict__ fc2b,
    const float* __restrict__ klpart, float* __restrict__ out) {
  int b = blockIdx.x, t = threadIdx.x;
  __shared__ float embedL[960];
  __shared__ float sred[32];
  __shared__ float coeff[8];
  __shared__ float hL[64];
  float part[8] = {0, 0, 0, 0, 0, 0, 0, 0};
  for (int j = t; j < 960; j += 256) {
    float w = wl[j];
#pragma unroll
    for (int l = 0; l < 8; ++l) part[l] += gall[l * 30720 + b * 960 + j] * w;
  }
#pragma unroll
  for (int off = 32; off > 0; off >>= 1) {
#pragma unroll
    for (int l = 0; l < 8; ++l) part[l] += __shfl_down(part[l], off, 64);
  }
  int wv = t >> 6, lane = t & 63;
  if (lane == 0) {
#pragma unroll
    for (int l = 0; l < 8; ++l) sred[l * 4 + wv] = part[l];
  }
  __syncthreads();
  if (t == 0) {
    float s[8], mx = -3.402823466e38f;
#pragma unroll
    for (int l = 0; l < 8; ++l) {
      s[l] = sred[l * 4] + sred[l * 4 + 1] + sred[l * 4 + 2] + sred[l * 4 + 3];
      mx = fmaxf(mx, s[l]);
    }
    float se = 0.f;
#pragma unroll
    for (int l = 0; l < 8; ++l) {
      s[l] = expf(s[l] - mx);
      se += s[l];
    }
#pragma unroll
    for (int l = 0; l < 8; ++l) coeff[l] = s[l] / se;
  }
  __syncthreads();
  for (int j = t; j < 960; j += 256) {
    float e = 0.f;
#pragma unroll
    for (int l = 0; l < 8; ++l) e += gall[l * 30720 + b * 960 + j] * coeff[l];
    embedL[j] = e;
  }
  __syncthreads();
  if (t < 64) {
    float h = fc1b[t];
    for (int j = 0; j < 960; ++j) h += embedL[j] * fc1w[t * 960 + j];
    hL[t] = h;
  }
  __syncthreads();
  if (t < 3) {
    float o = fc2b[t];
#pragma unroll
    for (int j = 0; j < 64; ++j) o += hL[j] * fc2w[t * 64 + j];
    out[b * 3 + t] = o;
  }
  if (b == 0 && t == 4) {
    float kl = 0.f;
    for (int dd = 0; dd < 30; ++dd) kl += klpart[dd];
    out[96] = kl;
  }
}

// =====================================================================
extern "C" void kernel_launch(void* const* d_in, const int* in_sizes, int n_in,
                              void* d_out, int out_size, void* d_ws,
                              size_t ws_size, hipStream_t stream) {
  (void)in_sizes; (void)n_in; (void)out_size; (void)ws_size;
  const float* x = (const float*)d_in[0];
  const float* adj = (const float*)d_in[1];
  const int* num_node = (const int*)d_in[2];
  const float* dict_feat = (const float*)d_in[3];
  const float* dict_adj = (const float*)d_in[4];
  const int* dict_nnode = (const int*)d_in[5];
  const float* eW1 = (const float*)d_in[6];
  const float* eb1 = (const float*)d_in[7];
  const float* eW2 = (const float*)d_in[8];
  const float* eb2 = (const float*)d_in[9];
  const float* eW3 = (const float*)d_in[10];
  const float* eb3 = (const float*)d_in[11];
  const float* dW1 = (const float*)d_in[12];
  const float* db1 = (const float*)d_in[13];
  const float* dW2 = (const float*)d_in[14];
  const float* db2 = (const float*)d_in[15];
  const float* dW3 = (const float*)d_in[16];
  const float* db3 = (const float*)d_in[17];
  const float* mlp_w = (const float*)d_in[18];
  const float* mlp_b = (const float*)d_in[19];
  const float* mlp2_w = (const float*)d_in[20];
  const float* mlp2_b = (const float*)d_in[21];
  const float* dist_para = (const float*)d_in[22];
  const float* weight_lamda = (const float*)d_in[23];
  const float* fc1_w = (const float*)d_in[24];
  const float* fc1_b = (const float*)d_in[25];
  const float* fc2_w = (const float*)d_in[26];
  const float* fc2_b = (const float*)d_in[27];

  float* ws = (float*)d_ws;
  float* xe = ws + OFF_XE;
  float* de = ws + OFF_DE;
  float* dsb = ws + OFF_DS;
  float* x2b = ws + OFF_X2;
  float* y2b = ws + OFF_Y2;
  float* zb = ws + OFF_Z;
  float* c0b = ws + OFF_C0;
  float* klb = ws + OFF_KL;
  float* gall = ws + OFF_GALL;
  float* Wbuf = ws + OFF_WBUF;

  gcn_kernel<<<62, 256, 0, stream>>>(x, adj, eW1, eb1, eW2, eb2, eW3, eb3,
                                     dict_feat, dict_adj, dW1, db1, dW2, db2,
                                     dW3, db3, xe, de, x2b);
  z_kernel<<<1, 256, 0, stream>>>(xe, mlp_w, mlp_b, mlp2_w, mlp2_b, zb, c0b);
  attn_kernel<<<30, 64, 0, stream>>>(de, zb, c0b, dsb, y2b, klb);
  sink_kernel<<<960, 256, 0, stream>>>(xe, dsb, x2b, y2b, num_node,
                                       dict_nnode, Wbuf);
  gd_gemm_kernel<<<960, 256, 0, stream>>>(Wbuf, dist_para, gall);
  final_kernel<<<32, 256, 0, stream>>>(gall, weight_lamda, fc1_w, fc1_b, fc2_w,
                                       fc2_b, klb, (float*)d_out);
}

// Round 4
// 434.310 us; speedup vs baseline: 1.1015x; 1.1015x over previous
//
#include <hip/hip_runtime.h>
#include <hip/hip_bf16.h>

// Problem constants
// B=32, N=64, D=30, ND=64, F0=64, H1=128, H2=64, H3=32, L=8, SINK_K=10
// LAMDA = {0.01,0.1,0.5,1.0,3.0,5.0,10.0,20.0}, P0=0.5, EPS=1e-6

__device__ __constant__ float c_LAM[8] = {0.01f, 0.1f, 0.5f, 1.0f, 3.0f, 5.0f, 10.0f, 20.0f};

// ---------------- workspace layout (float offsets) ----------------
constexpr int OFF_XE   = 0;         // 32*64*32 = 65536
constexpr int OFF_DE   = 65536;     // 30*64*32 = 61440
constexpr int OFF_DS   = 126976;    // 30*64*32 = 61440
constexpr int OFF_X2   = 188416;    // 2048
constexpr int OFF_Y2   = 190464;    // 1920
constexpr int OFF_Z    = 192384;    // 32
constexpr int OFF_C0   = 192416;    // 16
constexpr int OFF_KL   = 192432;    // 48
constexpr int OFF_GALL = 192480;    // 8*32*960 = 245760
constexpr int OFF_WBUF = 438272;    // bf16: 7680*4096*2 B = 63 MB

// wave-uniform broadcast of another lane's value (idx must be wave-uniform)
__device__ __forceinline__ float lane_bcast(float v, int lane) {
  return __int_as_float(__builtin_amdgcn_readlane(__float_as_int(v), lane));
}

// fp32 -> bf16 bits, round-to-nearest-even
__device__ __forceinline__ unsigned bf16_bits(float f) {
  unsigned u = __float_as_uint(f);
  return (u + 0x7fffu + ((u >> 16) & 1u)) >> 16;
}

// =====================================================================
// GCN encoder: one block per graph (blocks 0..31 = x-encoder, 32..61 = dict)
// =====================================================================
template <int K, int J>
__device__ __forceinline__ void mm64(const float* __restrict__ A, int lda,
                                     const float* __restrict__ W,
                                     float* __restrict__ C,
                                     const float* __restrict__ bias,
                                     bool do_relu, int t) {
  constexpr int JT = J >> 2;        // float4 tiles per row
  constexpr int TILES = 16 * JT;    // 16 i-tiles (64 rows / 4)
  for (int task = t; task < TILES; task += 256) {
    int i4 = task / JT;
    int j4 = task - i4 * JT;
    const float* a0 = A + (i4 * 4 + 0) * lda;
    const float* a1 = a0 + lda;
    const float* a2 = a1 + lda;
    const float* a3 = a2 + lda;
    float acc[4][4];
#pragma unroll
    for (int r = 0; r < 4; ++r)
#pragma unroll
      for (int c = 0; c < 4; ++c) acc[r][c] = 0.0f;
    const float* wp = W + j4 * 4;
#pragma unroll 8
    for (int k = 0; k < K; ++k) {
      float4 w = *(const float4*)(wp + k * J);
      float v0 = a0[k], v1 = a1[k], v2 = a2[k], v3 = a3[k];
      acc[0][0] += v0 * w.x; acc[0][1] += v0 * w.y; acc[0][2] += v0 * w.z; acc[0][3] += v0 * w.w;
      acc[1][0] += v1 * w.x; acc[1][1] += v1 * w.y; acc[1][2] += v1 * w.z; acc[1][3] += v1 * w.w;
      acc[2][0] += v2 * w.x; acc[2][1] += v2 * w.y; acc[2][2] += v2 * w.z; acc[2][3] += v2 * w.w;
      acc[3][0] += v3 * w.x; acc[3][1] += v3 * w.y; acc[3][2] += v3 * w.z; acc[3][3] += v3 * w.w;
    }
    float4 bv = make_float4(0.f, 0.f, 0.f, 0.f);
    if (bias) bv = *(const float4*)(bias + j4 * 4);
#pragma unroll
    for (int r = 0; r < 4; ++r) {
      float o0 = acc[r][0] + bv.x, o1 = acc[r][1] + bv.y;
      float o2 = acc[r][2] + bv.z, o3 = acc[r][3] + bv.w;
      if (do_relu) {
        o0 = fmaxf(o0, 0.f); o1 = fmaxf(o1, 0.f);
        o2 = fmaxf(o2, 0.f); o3 = fmaxf(o3, 0.f);
      }
      float4 st = make_float4(o0, o1, o2, o3);
      *(float4*)(C + (i4 * 4 + r) * J + j4 * 4) = st;
    }
  }
}

__global__ __launch_bounds__(256) void gcn_kernel(
    const float* __restrict__ x, const float* __restrict__ adj,
    const float* __restrict__ eW1, const float* __restrict__ eb1,
    const float* __restrict__ eW2, const float* __restrict__ eb2,
    const float* __restrict__ eW3, const float* __restrict__ eb3,
    const float* __restrict__ dx, const float* __restrict__ dadj,
    const float* __restrict__ dW1, const float* __restrict__ db1,
    const float* __restrict__ dW2, const float* __restrict__ db2,
    const float* __restrict__ dW3, const float* __restrict__ db3,
    float* __restrict__ xe, float* __restrict__ de,
    float* __restrict__ x2b) {
  __shared__ __align__(16) float C0[64 * 128];
  __shared__ __align__(16) float C1[64 * 128];
  int t = threadIdx.x;
  const float *src, *ad, *W1, *b1, *W2, *b2, *W3, *b3;
  float* outp;
  bool is_x = (blockIdx.x < 32);
  int g;
  if (is_x) {
    g = blockIdx.x;
    src = x + g * 4096; ad = adj + g * 4096;
    W1 = eW1; b1 = eb1; W2 = eW2; b2 = eb2; W3 = eW3; b3 = eb3;
    outp = xe + g * 2048;
  } else {
    g = blockIdx.x - 32;
    src = dx + g * 4096; ad = dadj + g * 4096;
    W1 = dW1; b1 = db1; W2 = dW2; b2 = db2; W3 = dW3; b3 = db3;
    outp = de + g * 2048;
  }
  mm64<64, 128>(src, 64, W1, C1, nullptr, false, t);
  __syncthreads();
  mm64<64, 128>(ad, 64, C1, C0, b1, true, t);
  __syncthreads();
  mm64<128, 64>(C0, 128, W2, C1, nullptr, false, t);
  __syncthreads();
  mm64<64, 64>(ad, 64, C1, C0, b2, true, t);
  __syncthreads();
  mm64<64, 32>(C0, 64, W3, C1, nullptr, false, t);
  __syncthreads();
  mm64<64, 32>(ad, 64, C1, outp, b3, false, t);
  __syncthreads();
  if (is_x && t < 64) {
    const float* r = outp + t * 32;
    float s = 0.f;
#pragma unroll
    for (int f = 0; f < 32; ++f) s += r[f] * r[f];
    x2b[g * 64 + t] = s;
  }
}

// =====================================================================
__global__ __launch_bounds__(256) void z_kernel(
    const float* __restrict__ xe, const float* __restrict__ mlp_w,
    const float* __restrict__ mlp_b, const float* __restrict__ mlp2_w,
    const float* __restrict__ mlp2_b, float* __restrict__ z,
    float* __restrict__ c0) {
  __shared__ float yb[32 * 33];
  int t = threadIdx.x;
  for (int idx = t; idx < 1024; idx += 256) {
    int b = idx >> 5, f = idx & 31;
    float s = 0.f, sb = 0.f;
    for (int n = 0; n < 64; ++n) {
      float v = xe[b * 2048 + n * 32 + f];
      s += v * v;
      sb += v * mlp_w[n];
    }
    yb[b * 33 + f] = sb / (sqrtf(s) + 1e-12f);
  }
  __syncthreads();
  if (t < 32) {
    float zz = 0.f;
    for (int b = 0; b < 32; ++b) zz += yb[b * 33 + t] * mlp2_w[b];
    z[t] = zz;
    if (t == 0) {
      float sm2 = 0.f;
      for (int b = 0; b < 32; ++b) sm2 += mlp2_w[b];
      c0[0] = mlp_b[0] * sm2 + mlp2_b[0];
    }
  }
}

// =====================================================================
// JAX threefry2x32, key = (0, 42)
// =====================================================================
__device__ __forceinline__ unsigned rotl32(unsigned v, int s) {
  return (v << s) | (v >> (32 - s));
}
__device__ __forceinline__ void threefry42(unsigned x0, unsigned x1,
                                           unsigned& o0, unsigned& o1) {
  const unsigned ks0 = 0u, ks1 = 42u, ks2 = 0x1BD11BDAu ^ 0u ^ 42u;
  unsigned ks[3] = {ks0, ks1, ks2};
  x0 += ks[0];
  x1 += ks[1];
  const int R[2][4] = {{13, 15, 26, 6}, {17, 29, 16, 24}};
#pragma unroll
  for (int r = 0; r < 5; ++r) {
    const int* rr = R[r & 1];
#pragma unroll
    for (int i = 0; i < 4; ++i) {
      x0 += x1;
      x1 = rotl32(x1, rr[i]);
      x1 ^= x0;
    }
    x0 += ks[(r + 1) % 3];
    x1 += ks[(r + 2) % 3] + (unsigned)(r + 1);
  }
  o0 = x0;
  o1 = x1;
}

// =====================================================================
__global__ __launch_bounds__(64) void attn_kernel(
    const float* __restrict__ de, const float* __restrict__ z,
    const float* __restrict__ c0, float* __restrict__ dsamp,
    float* __restrict__ y2, float* __restrict__ klpart) {
  int d = blockIdx.x, m = threadIdx.x;
  __shared__ float dn[32];
  if (m < 32) {
    float s = 0.f;
    for (int n = 0; n < 64; ++n) {
      float v = de[d * 2048 + n * 32 + m];
      s += v * v;
    }
    dn[m] = sqrtf(s) + 1e-12f;
  }
  __syncthreads();
  const float* row = de + d * 2048 + m * 32;
  float logit = c0[0], s2 = 0.f;
#pragma unroll 8
  for (int f = 0; f < 32; ++f) {
    float v = row[f];
    logit += (v / dn[f]) * z[f];
    s2 += v * v;
  }
  float attn = 1.0f / (1.0f + expf(-logit));
  int e = d * 64 + m;
  unsigned o0, o1, bits;
  if (e < 960) {
    threefry42((unsigned)e, (unsigned)(960 + e), o0, o1);
    bits = o0;
  } else {
    threefry42((unsigned)(e - 960), (unsigned)e, o0, o1);
    bits = o1;
  }
  float u = __uint_as_float((bits >> 9) | 0x3f800000u) - 1.0f;
  u = fmaxf(u, 0.0f);
  float bern = (u < attn) ? 1.0f : 0.0f;
  float* dr = dsamp + d * 2048 + m * 32;
#pragma unroll 8
  for (int f = 0; f < 32; ++f) dr[f] = bern * row[f];
  y2[e] = bern * s2;
  float klt = attn * logf(2.0f * attn) + (1.0f - attn) * logf(2.0f * (1.0f - attn));
#pragma unroll
  for (int off = 32; off > 0; off >>= 1) klt += __shfl_down(klt, off, 64);
  if (m == 0) klpart[d] = klt;
}

// =====================================================================
// Sinkhorn: grid = 1920 = 960 (b,d) x 2 lambda-halves; 4 lambdas per block.
// K in LDS; 16-elem register fragments per thread; u,v in lane registers
// (each wave holds the full 64-vector redundantly; broadcast via readlane).
// 2 barriers per Sinkhorn iteration (ping-pong scratch).
// W output stored bf16 (RNE), packed pairs, coalesced.
// =====================================================================
__global__ __launch_bounds__(256) void sink_kernel(
    const float* __restrict__ xe, const float* __restrict__ ds,
    const float* __restrict__ x2g, const float* __restrict__ y2g,
    const int* __restrict__ num_node, const int* __restrict__ dict_nnode,
    __hip_bfloat16* __restrict__ Wbuf) {
  __shared__ __align__(16) float Ms[64 * 65];   // 16640 B
  __shared__ __align__(16) float KM[64 * 67];   // 17152 B (aliases staging)
  __shared__ float w1s[64], w2s[64], x2s[64], y2s[64];
  __shared__ float us[64], vs[64], rmS[64], riS[64];
  __shared__ float scrA[256], scrB[256];

  int t = threadIdx.x;
  int m = t & 63;
  int q = t >> 6;
  int bd = blockIdx.x >> 1;
  int half = blockIdx.x & 1;
  int b = bd / 30;
  int d = bd - b * 30;

  // stage xe/ds into the KM region (overwritten after Ms is built)
  float* XEp = KM;          // 64*33 = 2112
  float* DSp = KM + 2112;   // 64*33 = 2112 (4224 <= 4288)
  {
    const float* xsrc = xe + b * 2048;
    const float* dsrc = ds + d * 2048;
    for (int i = t; i < 2048; i += 256) {
      int r = i >> 5, c = i & 31;
      XEp[r * 33 + c] = xsrc[i];
      DSp[r * 33 + c] = dsrc[i];
    }
  }
  if (t < 64) {
    int nn = num_node[b], dnn = dict_nnode[d];
    w1s[t] = (t < nn) ? 1.0f / (float)nn : 0.0f;
    w2s[t] = (t < dnn) ? 1.0f / (float)dnn : 0.0f;
    x2s[t] = x2g[b * 64 + t];
    y2s[t] = y2g[d * 64 + t];
  }
  __syncthreads();
  // M[i][j] = x2[i] + y2[j] - 2 <xe_i, ds_j>
  for (int idx = t; idx < 4096; idx += 256) {
    int i = idx >> 6, j = idx & 63;
    const float* xr = XEp + i * 33;
    const float* dr = DSp + j * 33;
    float acc = 0.f;
#pragma unroll
    for (int f = 0; f < 32; ++f) acc += xr[f] * dr[f];
    Ms[i * 65 + j] = x2s[i] + y2s[j] - 2.0f * acc;
  }
  __syncthreads();

  float w1m = w1s[m], w2m = w2s[m];

  for (int lrep = 0; lrep < 4; ++lrep) {
    int l = half * 4 + lrep;
    float lam = c_LAM[l];
    // KM = exp(-lam*M) * mask  (overwrites staging on first lrep)
    for (int idx = t; idx < 4096; idx += 256) {
      int i = idx >> 6, j = idx & 63;
      float kv = 0.0f;
      if (w1s[i] > 0.0f && w2s[j] > 0.0f) kv = __expf(-lam * Ms[i * 65 + j]);
      KM[i * 67 + j] = kv;
    }
    __syncthreads();

    // register fragments: kreg = column m rows [q*16,+16); kregT = row m cols [q*16,+16)
    float kreg[16], kregT[16];
#pragma unroll
    for (int nn = 0; nn < 16; ++nn) {
      kreg[nn] = KM[(q * 16 + nn) * 67 + m];
      kregT[nn] = KM[m * 67 + q * 16 + nn];
    }

    float u = 1.0f, v = 0.0f;
    for (int it = 0; it < 10; ++it) {
      // tv[m] partial over i in wave's chunk; u[i] broadcast from own wave's lanes
      {
        float s0 = 0.f, s1 = 0.f;
#pragma unroll
        for (int nn = 0; nn < 16; nn += 2) {
          s0 = fmaf(kreg[nn], lane_bcast(u, q * 16 + nn), s0);
          s1 = fmaf(kreg[nn + 1], lane_bcast(u, q * 16 + nn + 1), s1);
        }
        scrA[t] = s0 + s1;
      }
      __syncthreads();
      v = w2m / (scrA[m] + scrA[64 + m] + scrA[128 + m] + scrA[192 + m] + 1e-6f);
      {
        float s0 = 0.f, s1 = 0.f;
#pragma unroll
        for (int nn = 0; nn < 16; nn += 2) {
          s0 = fmaf(kregT[nn], lane_bcast(v, q * 16 + nn), s0);
          s1 = fmaf(kregT[nn + 1], lane_bcast(v, q * 16 + nn + 1), s1);
        }
        scrB[t] = s0 + s1;
      }
      __syncthreads();
      u = w1m / (scrB[m] + scrB[64 + m] + scrB[128 + m] + scrB[192 + m] + 1e-6f);
    }

    // row min/max of G = u[i] K[i][j] v[j] (partial over this wave's j-chunk)
    {
      float mx = -3.402823466e38f, mn = 3.402823466e38f;
#pragma unroll
      for (int nn = 0; nn < 16; ++nn) {
        float g = u * kregT[nn] * lane_bcast(v, q * 16 + nn);
        mx = fmaxf(mx, g);
        mn = fminf(mn, g);
      }
      scrA[t] = mx;
      scrB[t] = mn;
    }
    if (q == 0) {
      us[m] = u;
      vs[m] = v;
    }
    __syncthreads();
    if (q == 0) {
      float mx = fmaxf(fmaxf(scrA[m], scrA[64 + m]), fmaxf(scrA[128 + m], scrA[192 + m]));
      float mn = fminf(fminf(scrB[m], scrB[64 + m]), fminf(scrB[128 + m], scrB[192 + m]));
      rmS[m] = mn;
      riS[m] = 1.0f / (mx - mn + 1e-6f);
    }
    __syncthreads();

    // W-write: bf16 pairs, coalesced 4B stores
    unsigned* wrow =
        (unsigned*)(Wbuf + (size_t)((l * 32 + b) * 30 + d) * 4096);
#pragma unroll
    for (int e = 0; e < 8; ++e) {
      int idx2 = e * 256 + t;       // pair index 0..2047
      int i = idx2 >> 5;
      int j0 = (idx2 & 31) * 2;
      float ui_ = us[i], rm = rmS[i], ri = riS[i];
      float g0 = ui_ * KM[i * 67 + j0] * vs[j0];
      float w0 = (g0 - rm) * ri * Ms[i * 65 + j0];
      float g1 = ui_ * KM[i * 67 + j0 + 1] * vs[j0 + 1];
      float w1 = (g1 - rm) * ri * Ms[i * 65 + j0 + 1];
      wrow[idx2] = bf16_bits(w0) | (bf16_bits(w1) << 16);
    }
    __syncthreads();  // protect KM before next lambda overwrites it
  }
}

// =====================================================================
// gall(7680x32) = Wbuf(7680x4096, bf16) @ dp(4096x32, fp32)
// 960 blocks x 256 thr, 8 rows/block; thread (kg=t>>3, col4=t&7);
// 16 steps x 8 k: W loaded as uint4 (8 bf16), dp as float4.
// =====================================================================
__global__ __launch_bounds__(256) void gd_gemm_kernel(
    const __hip_bfloat16* __restrict__ Wbuf, const float* __restrict__ dp,
    float* __restrict__ gall) {
  __shared__ __align__(16) float4 red[4 * 8 * 8];  // [wave][row][col4]
  int t = threadIdx.x;
  int col4 = t & 7;
  int kg = t >> 3;          // 0..31
  int wv = t >> 6;          // 0..3
  int r0 = blockIdx.x << 3; // 8 rows per block
  const float4* dp4 = (const float4*)dp;
  const unsigned* Wb = (const unsigned*)(Wbuf + (size_t)r0 * 4096);

  float4 acc[8];
#pragma unroll
  for (int r = 0; r < 8; ++r) acc[r] = make_float4(0.f, 0.f, 0.f, 0.f);

  for (int s = 0; s < 16; ++s) {
    int kb = s * 256 + kg * 8;
    float4 dv[8];
#pragma unroll
    for (int kk = 0; kk < 8; ++kk) dv[kk] = dp4[(kb + kk) * 8 + col4];
#pragma unroll
    for (int r = 0; r < 8; ++r) {
      uint4 wq = *(const uint4*)(Wb + r * 2048 + (kb >> 1));
      float f0 = __uint_as_float(wq.x << 16);
      float f1 = __uint_as_float(wq.x & 0xffff0000u);
      float f2 = __uint_as_float(wq.y << 16);
      float f3 = __uint_as_float(wq.y & 0xffff0000u);
      float f4 = __uint_as_float(wq.z << 16);
      float f5 = __uint_as_float(wq.z & 0xffff0000u);
      float f6 = __uint_as_float(wq.w << 16);
      float f7 = __uint_as_float(wq.w & 0xffff0000u);
      acc[r].x += f0 * dv[0].x + f1 * dv[1].x + f2 * dv[2].x + f3 * dv[3].x +
                  f4 * dv[4].x + f5 * dv[5].x + f6 * dv[6].x + f7 * dv[7].x;
      acc[r].y += f0 * dv[0].y + f1 * dv[1].y + f2 * dv[2].y + f3 * dv[3].y +
                  f4 * dv[4].y + f5 * dv[5].y + f6 * dv[6].y + f7 * dv[7].y;
      acc[r].z += f0 * dv[0].z + f1 * dv[1].z + f2 * dv[2].z + f3 * dv[3].z +
                  f4 * dv[4].z + f5 * dv[5].z + f6 * dv[6].z + f7 * dv[7].z;
      acc[r].w += f0 * dv[0].w + f1 * dv[1].w + f2 * dv[2].w + f3 * dv[3].w +
                  f4 * dv[4].w + f5 * dv[5].w + f6 * dv[6].w + f7 * dv[7].w;
    }
  }
  // reduce across kg (lane stride 8) within wave
#pragma unroll
  for (int off = 32; off >= 8; off >>= 1) {
#pragma unroll
    for (int r = 0; r < 8; ++r) {
      acc[r].x += __shfl_down(acc[r].x, off, 64);
      acc[r].y += __shfl_down(acc[r].y, off, 64);
      acc[r].z += __shfl_down(acc[r].z, off, 64);
      acc[r].w += __shfl_down(acc[r].w, off, 64);
    }
  }
  if ((t & 63) < 8) {
#pragma unroll
    for (int r = 0; r < 8; ++r) red[(wv * 8 + r) * 8 + col4] = acc[r];
  }
  __syncthreads();
  if (t < 64) {
    int r = t >> 3, c4 = t & 7;
    float4 s = red[(0 * 8 + r) * 8 + c4];
    float4 s1 = red[(1 * 8 + r) * 8 + c4];
    float4 s2 = red[(2 * 8 + r) * 8 + c4];
    float4 s3 = red[(3 * 8 + r) * 8 + c4];
    s.x += s1.x + s2.x + s3.x;
    s.y += s1.y + s2.y + s3.y;
    s.z += s1.z + s2.z + s3.z;
    s.w += s1.w + s2.w + s3.w;
    *(float4*)(gall + (size_t)(r0 + r) * 32 + c4 * 4) = s;
  }
}

// =====================================================================
__global__ __launch_bounds__(256) void final_kernel(
    const float* __restrict__ gall, const float* __restrict__ wl,
    const float* __restrict__ fc1w, const float* __restrict__ fc1b,
    const float* __restrict__ fc2w, const float* __restrict__ fc2b,
    const float* __restrict__ klpart, float* __restrict__ out) {
  int b = blockIdx.x, t = threadIdx.x;
  __shared__ float embedL[960];
  __shared__ float sred[32];
  __shared__ float coeff[8];
  __shared__ float hL[64];
  float part[8] = {0, 0, 0, 0, 0, 0, 0, 0};
  for (int j = t; j < 960; j += 256) {
    float w = wl[j];
#pragma unroll
    for (int l = 0; l < 8; ++l) part[l] += gall[l * 30720 + b * 960 + j] * w;
  }
#pragma unroll
  for (int off = 32; off > 0; off >>= 1) {
#pragma unroll
    for (int l = 0; l < 8; ++l) part[l] += __shfl_down(part[l], off, 64);
  }
  int wv = t >> 6, lane = t & 63;
  if (lane == 0) {
#pragma unroll
    for (int l = 0; l < 8; ++l) sred[l * 4 + wv] = part[l];
  }
  __syncthreads();
  if (t == 0) {
    float s[8], mx = -3.402823466e38f;
#pragma unroll
    for (int l = 0; l < 8; ++l) {
      s[l] = sred[l * 4] + sred[l * 4 + 1] + sred[l * 4 + 2] + sred[l * 4 + 3];
      mx = fmaxf(mx, s[l]);
    }
    float se = 0.f;
#pragma unroll
    for (int l = 0; l < 8; ++l) {
      s[l] = expf(s[l] - mx);
      se += s[l];
    }
#pragma unroll
    for (int l = 0; l < 8; ++l) coeff[l] = s[l] / se;
  }
  __syncthreads();
  for (int j = t; j < 960; j += 256) {
    float e = 0.f;
#pragma unroll
    for (int l = 0; l < 8; ++l) e += gall[l * 30720 + b * 960 + j] * coeff[l];
    embedL[j] = e;
  }
  __syncthreads();
  if (t < 64) {
    float h = fc1b[t];
    for (int j = 0; j < 960; ++j) h += embedL[j] * fc1w[t * 960 + j];
    hL[t] = h;
  }
  __syncthreads();
  if (t < 3) {
    float o = fc2b[t];
#pragma unroll
    for (int j = 0; j < 64; ++j) o += hL[j] * fc2w[t * 64 + j];
    out[b * 3 + t] = o;
  }
  if (b == 0 && t == 4) {
    float kl = 0.f;
    for (int dd = 0; dd < 30; ++dd) kl += klpart[dd];
    out[96] = kl;
  }
}

// =====================================================================
extern "C" void kernel_launch(void* const* d_in, const int* in_sizes, int n_in,
                              void* d_out, int out_size, void* d_ws,
                              size_t ws_size, hipStream_t stream) {
  (void)in_sizes; (void)n_in; (void)out_size; (void)ws_size;
  const float* x = (const float*)d_in[0];
  const float* adj = (const float*)d_in[1];
  const int* num_node = (const int*)d_in[2];
  const float* dict_feat = (const float*)d_in[3];
  const float* dict_adj = (const float*)d_in[4];
  const int* dict_nnode = (const int*)d_in[5];
  const float* eW1 = (const float*)d_in[6];
  const float* eb1 = (const float*)d_in[7];
  const float* eW2 = (const float*)d_in[8];
  const float* eb2 = (const float*)d_in[9];
  const float* eW3 = (const float*)d_in[10];
  const float* eb3 = (const float*)d_in[11];
  const float* dW1 = (const float*)d_in[12];
  const float* db1 = (const float*)d_in[13];
  const float* dW2 = (const float*)d_in[14];
  const float* db2 = (const float*)d_in[15];
  const float* dW3 = (const float*)d_in[16];
  const float* db3 = (const float*)d_in[17];
  const float* mlp_w = (const float*)d_in[18];
  const float* mlp_b = (const float*)d_in[19];
  const float* mlp2_w = (const float*)d_in[20];
  const float* mlp2_b = (const float*)d_in[21];
  const float* dist_para = (const float*)d_in[22];
  const float* weight_lamda = (const float*)d_in[23];
  const float* fc1_w = (const float*)d_in[24];
  const float* fc1_b = (const float*)d_in[25];
  const float* fc2_w = (const float*)d_in[26];
  const float* fc2_b = (const float*)d_in[27];

  float* ws = (float*)d_ws;
  float* xe = ws + OFF_XE;
  float* de = ws + OFF_DE;
  float* dsb = ws + OFF_DS;
  float* x2b = ws + OFF_X2;
  float* y2b = ws + OFF_Y2;
  float* zb = ws + OFF_Z;
  float* c0b = ws + OFF_C0;
  float* klb = ws + OFF_KL;
  float* gall = ws + OFF_GALL;
  __hip_bfloat16* Wbuf = (__hip_bfloat16*)(ws + OFF_WBUF);

  gcn_kernel<<<62, 256, 0, stream>>>(x, adj, eW1, eb1, eW2, eb2, eW3, eb3,
                                     dict_feat, dict_adj, dW1, db1, dW2, db2,
                                     dW3, db3, xe, de, x2b);
  z_kernel<<<1, 256, 0, stream>>>(xe, mlp_w, mlp_b, mlp2_w, mlp2_b, zb, c0b);
  attn_kernel<<<30, 64, 0, stream>>>(de, zb, c0b, dsb, y2b, klb);
  sink_kernel<<<1920, 256, 0, stream>>>(xe, dsb, x2b, y2b, num_node,
                                        dict_nnode, Wbuf);
  gd_gemm_kernel<<<960, 256, 0, stream>>>(Wbuf, dist_para, gall);
  final_kernel<<<32, 256, 0, stream>>>(gall, weight_lamda, fc1_w, fc1_b, fc2_w,
                                       fc2_b, klb, (float*)d_out);
}

// Round 5
// 394.555 us; speedup vs baseline: 1.2124x; 1.1008x over previous
//
#include <hip/hip_runtime.h>
#include <hip/hip_bf16.h>

// Problem constants
// B=32, N=64, D=30, ND=64, F0=64, H1=128, H2=64, H3=32, L=8, SINK_K=10
// LAMDA = {0.01,0.1,0.5,1.0,3.0,5.0,10.0,20.0}, P0=0.5, EPS=1e-6

__device__ __constant__ float c_LAM[8] = {0.01f, 0.1f, 0.5f, 1.0f, 3.0f, 5.0f, 10.0f, 20.0f};

// ---------------- workspace layout (float offsets) ----------------
constexpr int OFF_XE   = 0;         // 32*64*32 = 65536
constexpr int OFF_DE   = 65536;     // 30*64*32 = 61440
constexpr int OFF_DS   = 126976;    // 30*64*32 = 61440
constexpr int OFF_X2   = 188416;    // 2048
constexpr int OFF_Y2   = 190464;    // 1920
constexpr int OFF_YW   = 192384;    // 32*32 = 1024
constexpr int OFF_KL   = 193408;    // 64
constexpr int OFF_GALL = 193472;    // 8*32*960 = 245760

// wave-uniform broadcast of another lane's value (idx must be wave-uniform)
__device__ __forceinline__ float lane_bcast(float v, int lane) {
  return __int_as_float(__builtin_amdgcn_readlane(__float_as_int(v), lane));
}

// =====================================================================
// GCN encoder: one block per graph (blocks 0..31 = x-encoder, 32..61 = dict)
// src/adj staged into padded LDS (stride 65) to kill same-bank row reads.
// Epilogues: x2 (x blocks), yw[b][f] = mlp2_w[b] * yb[b,f] (x blocks).
// =====================================================================
template <int K, int J>
__device__ __forceinline__ void mm64(const float* __restrict__ A, int lda,
                                     const float* __restrict__ W,
                                     float* __restrict__ C,
                                     const float* __restrict__ bias,
                                     bool do_relu, int t) {
  constexpr int JT = J >> 2;        // float4 tiles per row
  constexpr int TILES = 16 * JT;    // 16 i-tiles (64 rows / 4)
  for (int task = t; task < TILES; task += 256) {
    int i4 = task / JT;
    int j4 = task - i4 * JT;
    const float* a0 = A + (i4 * 4 + 0) * lda;
    const float* a1 = a0 + lda;
    const float* a2 = a1 + lda;
    const float* a3 = a2 + lda;
    float acc[4][4];
#pragma unroll
    for (int r = 0; r < 4; ++r)
#pragma unroll
      for (int c = 0; c < 4; ++c) acc[r][c] = 0.0f;
    const float* wp = W + j4 * 4;
#pragma unroll 8
    for (int k = 0; k < K; ++k) {
      float4 w = *(const float4*)(wp + k * J);
      float v0 = a0[k], v1 = a1[k], v2 = a2[k], v3 = a3[k];
      acc[0][0] += v0 * w.x; acc[0][1] += v0 * w.y; acc[0][2] += v0 * w.z; acc[0][3] += v0 * w.w;
      acc[1][0] += v1 * w.x; acc[1][1] += v1 * w.y; acc[1][2] += v1 * w.z; acc[1][3] += v1 * w.w;
      acc[2][0] += v2 * w.x; acc[2][1] += v2 * w.y; acc[2][2] += v2 * w.z; acc[2][3] += v2 * w.w;
      acc[3][0] += v3 * w.x; acc[3][1] += v3 * w.y; acc[3][2] += v3 * w.z; acc[3][3] += v3 * w.w;
    }
    float4 bv = make_float4(0.f, 0.f, 0.f, 0.f);
    if (bias) bv = *(const float4*)(bias + j4 * 4);
#pragma unroll
    for (int r = 0; r < 4; ++r) {
      float o0 = acc[r][0] + bv.x, o1 = acc[r][1] + bv.y;
      float o2 = acc[r][2] + bv.z, o3 = acc[r][3] + bv.w;
      if (do_relu) {
        o0 = fmaxf(o0, 0.f); o1 = fmaxf(o1, 0.f);
        o2 = fmaxf(o2, 0.f); o3 = fmaxf(o3, 0.f);
      }
      float4 st = make_float4(o0, o1, o2, o3);
      *(float4*)(C + (i4 * 4 + r) * J + j4 * 4) = st;
    }
  }
}

__global__ __launch_bounds__(256) void gcn_kernel(
    const float* __restrict__ x, const float* __restrict__ adj,
    const float* __restrict__ eW1, const float* __restrict__ eb1,
    const float* __restrict__ eW2, const float* __restrict__ eb2,
    const float* __restrict__ eW3, const float* __restrict__ eb3,
    const float* __restrict__ dx, const float* __restrict__ dadj,
    const float* __restrict__ dW1, const float* __restrict__ db1,
    const float* __restrict__ dW2, const float* __restrict__ db2,
    const float* __restrict__ dW3, const float* __restrict__ db3,
    const float* __restrict__ mlp_w, const float* __restrict__ mlp2_w,
    float* __restrict__ xe, float* __restrict__ de,
    float* __restrict__ x2b, float* __restrict__ yw) {
  __shared__ float As[64 * 65];
  __shared__ float Aa[64 * 65];
  __shared__ __align__(16) float C0[64 * 128];
  __shared__ __align__(16) float C1[64 * 128];
  int t = threadIdx.x;
  const float *src, *ad, *W1, *b1, *W2, *b2, *W3, *b3;
  float* outp;
  bool is_x = (blockIdx.x < 32);
  int g;
  if (is_x) {
    g = blockIdx.x;
    src = x + g * 4096; ad = adj + g * 4096;
    W1 = eW1; b1 = eb1; W2 = eW2; b2 = eb2; W3 = eW3; b3 = eb3;
    outp = xe + g * 2048;
  } else {
    g = blockIdx.x - 32;
    src = dx + g * 4096; ad = dadj + g * 4096;
    W1 = dW1; b1 = db1; W2 = dW2; b2 = db2; W3 = dW3; b3 = db3;
    outp = de + g * 2048;
  }
  // stage src/adj into padded LDS
  {
    const float4* s4 = (const float4*)src;
    const float4* a4 = (const float4*)ad;
    for (int idx = t; idx < 1024; idx += 256) {
      int r = idx >> 4, c = (idx & 15) * 4;
      float4 v = s4[idx];
      As[r * 65 + c] = v.x; As[r * 65 + c + 1] = v.y;
      As[r * 65 + c + 2] = v.z; As[r * 65 + c + 3] = v.w;
      float4 w = a4[idx];
      Aa[r * 65 + c] = w.x; Aa[r * 65 + c + 1] = w.y;
      Aa[r * 65 + c + 2] = w.z; Aa[r * 65 + c + 3] = w.w;
    }
  }
  __syncthreads();
  mm64<64, 128>(As, 65, W1, C1, nullptr, false, t);
  __syncthreads();
  mm64<64, 128>(Aa, 65, C1, C0, b1, true, t);
  __syncthreads();
  mm64<128, 64>(C0, 128, W2, C1, nullptr, false, t);
  __syncthreads();
  mm64<64, 64>(Aa, 65, C1, C0, b2, true, t);
  __syncthreads();
  mm64<64, 32>(C0, 64, W3, C1, nullptr, false, t);
  __syncthreads();
  mm64<64, 32>(Aa, 65, C1, outp, b3, false, t);
  __syncthreads();
  if (is_x) {
    if (t < 64) {
      const float* r = outp + t * 32;
      float s = 0.f;
#pragma unroll
      for (int f = 0; f < 32; ++f) s += r[f] * r[f];
      x2b[g * 64 + t] = s;
    } else if (t < 96) {
      int f = t - 64;
      float s = 0.f, sb = 0.f;
      for (int n = 0; n < 64; ++n) {
        float v = outp[n * 32 + f];
        s += v * v;
        sb += v * mlp_w[n];
      }
      yw[g * 32 + f] = mlp2_w[g] * sb / (sqrtf(s) + 1e-12f);
    }
  }
}

// =====================================================================
// JAX threefry2x32, key = (0, 42)
// =====================================================================
__device__ __forceinline__ unsigned rotl32(unsigned v, int s) {
  return (v << s) | (v >> (32 - s));
}
__device__ __forceinline__ void threefry42(unsigned x0, unsigned x1,
                                           unsigned& o0, unsigned& o1) {
  const unsigned ks0 = 0u, ks1 = 42u, ks2 = 0x1BD11BDAu ^ 0u ^ 42u;
  unsigned ks[3] = {ks0, ks1, ks2};
  x0 += ks[0];
  x1 += ks[1];
  const int R[2][4] = {{13, 15, 26, 6}, {17, 29, 16, 24}};
#pragma unroll
  for (int r = 0; r < 5; ++r) {
    const int* rr = R[r & 1];
#pragma unroll
    for (int i = 0; i < 4; ++i) {
      x0 += x1;
      x1 = rotl32(x1, rr[i]);
      x1 ^= x0;
    }
    x0 += ks[(r + 1) % 3];
    x1 += ks[(r + 2) % 3] + (unsigned)(r + 1);
  }
  o0 = x0;
  o1 = x1;
}

// =====================================================================
// attn: grid 30 (d), 256 threads. Computes z (from yw partials), dn norms,
// c0, then attn/bern/dsamp/y2/kl.
// =====================================================================
__global__ __launch_bounds__(256) void attn_kernel(
    const float* __restrict__ de, const float* __restrict__ yw,
    const float* __restrict__ mlp_b, const float* __restrict__ mlp2_w,
    const float* __restrict__ mlp2_b, float* __restrict__ dsamp,
    float* __restrict__ y2, float* __restrict__ klpart) {
  int d = blockIdx.x, t = threadIdx.x;
  __shared__ float zs[32], dns[32], c0s[1];
  if (t < 32) {
    float zz = 0.f;
    for (int b = 0; b < 32; ++b) zz += yw[b * 32 + t];
    zs[t] = zz;
  } else if (t < 64) {
    int f = t - 32;
    float s = 0.f;
    for (int n = 0; n < 64; ++n) {
      float v = de[d * 2048 + n * 32 + f];
      s += v * v;
    }
    dns[f] = sqrtf(s) + 1e-12f;
  } else if (t == 64) {
    float sm2 = 0.f;
    for (int b = 0; b < 32; ++b) sm2 += mlp2_w[b];
    c0s[0] = mlp_b[0] * sm2 + mlp2_b[0];
  }
  __syncthreads();
  if (t < 64) {
    int m = t;
    const float* row = de + d * 2048 + m * 32;
    float logit = c0s[0], s2 = 0.f;
#pragma unroll 8
    for (int f = 0; f < 32; ++f) {
      float v = row[f];
      logit += (v / dns[f]) * zs[f];
      s2 += v * v;
    }
    float attn = 1.0f / (1.0f + expf(-logit));
    int e = d * 64 + m;
    unsigned o0, o1, bits;
    if (e < 960) {
      threefry42((unsigned)e, (unsigned)(960 + e), o0, o1);
      bits = o0;
    } else {
      threefry42((unsigned)(e - 960), (unsigned)e, o0, o1);
      bits = o1;
    }
    float u = __uint_as_float((bits >> 9) | 0x3f800000u) - 1.0f;
    u = fmaxf(u, 0.0f);
    float bern = (u < attn) ? 1.0f : 0.0f;
    float* dr = dsamp + d * 2048 + m * 32;
#pragma unroll 8
    for (int f = 0; f < 32; ++f) dr[f] = bern * row[f];
    y2[e] = bern * s2;
    float klt = attn * logf(2.0f * attn) + (1.0f - attn) * logf(2.0f * (1.0f - attn));
#pragma unroll
    for (int off = 32; off > 0; off >>= 1) klt += __shfl_down(klt, off, 64);
    if (m == 0) klpart[d] = klt;
  }
}

// =====================================================================
// Fused Sinkhorn + gd GEMV. One block per (b,d), 8 lambdas sequential.
// Per lambda: KM in LDS, 16-frag registers, 2-barrier iterations
// (u,v in lane registers, readlane broadcast). u/v/rmin/rinv stored per
// lambda; afterwards one G-phase pass reads each dist_para element once
// per block, recomputing K via exp, accumulating gd for all 8 lambdas.
// =====================================================================
__global__ __launch_bounds__(256) void sink_kernel(
    const float* __restrict__ xe, const float* __restrict__ ds,
    const float* __restrict__ x2g, const float* __restrict__ y2g,
    const int* __restrict__ num_node, const int* __restrict__ dict_nnode,
    const float* __restrict__ dp, float* __restrict__ gall) {
  __shared__ __align__(16) float Ms[64 * 65];   // 16640 B
  __shared__ __align__(16) float KM[64 * 67];   // 17152 B (aliases staging & scrG)
  __shared__ float w1s[64], w2s[64], x2s[64], y2s[64];
  __shared__ float uiL[8 * 64], viL[8 * 64], rmL[8 * 64], riL[8 * 64];
  __shared__ float scrA[256], scrB[256];

  int t = threadIdx.x;
  int m = t & 63;
  int wq = t >> 6;
  int b = blockIdx.x / 30;
  int d = blockIdx.x - b * 30;

  // stage xe/ds into KM region
  float* XEp = KM;          // 64*33
  float* DSp = KM + 2112;   // 64*33
  {
    const float* xsrc = xe + b * 2048;
    const float* dsrc = ds + d * 2048;
    for (int i = t; i < 2048; i += 256) {
      int r = i >> 5, c = i & 31;
      XEp[r * 33 + c] = xsrc[i];
      DSp[r * 33 + c] = dsrc[i];
    }
  }
  if (t < 64) {
    int nn = num_node[b], dnn = dict_nnode[d];
    w1s[t] = (t < nn) ? 1.0f / (float)nn : 0.0f;
    w2s[t] = (t < dnn) ? 1.0f / (float)dnn : 0.0f;
    x2s[t] = x2g[b * 64 + t];
    y2s[t] = y2g[d * 64 + t];
  }
  __syncthreads();
  for (int idx = t; idx < 4096; idx += 256) {
    int i = idx >> 6, j = idx & 63;
    const float* xr = XEp + i * 33;
    const float* dr = DSp + j * 33;
    float acc = 0.f;
#pragma unroll
    for (int f = 0; f < 32; ++f) acc += xr[f] * dr[f];
    Ms[i * 65 + j] = x2s[i] + y2s[j] - 2.0f * acc;
  }
  __syncthreads();

  float w1m = w1s[m], w2m = w2s[m];

  for (int l = 0; l < 8; ++l) {
    float lam = c_LAM[l];
    for (int idx = t; idx < 4096; idx += 256) {
      int i = idx >> 6, j = idx & 63;
      float kv = 0.0f;
      if (w1s[i] > 0.0f && w2s[j] > 0.0f) kv = __expf(-lam * Ms[i * 65 + j]);
      KM[i * 67 + j] = kv;
    }
    __syncthreads();

    float kreg[16], kregT[16];
#pragma unroll
    for (int nn = 0; nn < 16; ++nn) {
      kreg[nn] = KM[(wq * 16 + nn) * 67 + m];
      kregT[nn] = KM[m * 67 + wq * 16 + nn];
    }

    float u = 1.0f, v = 0.0f;
    for (int it = 0; it < 10; ++it) {
      {
        float s0 = 0.f, s1 = 0.f;
#pragma unroll
        for (int nn = 0; nn < 16; nn += 2) {
          s0 = fmaf(kreg[nn], lane_bcast(u, wq * 16 + nn), s0);
          s1 = fmaf(kreg[nn + 1], lane_bcast(u, wq * 16 + nn + 1), s1);
        }
        scrA[t] = s0 + s1;
      }
      __syncthreads();
      v = w2m / (scrA[m] + scrA[64 + m] + scrA[128 + m] + scrA[192 + m] + 1e-6f);
      {
        float s0 = 0.f, s1 = 0.f;
#pragma unroll
        for (int nn = 0; nn < 16; nn += 2) {
          s0 = fmaf(kregT[nn], lane_bcast(v, wq * 16 + nn), s0);
          s1 = fmaf(kregT[nn + 1], lane_bcast(v, wq * 16 + nn + 1), s1);
        }
        scrB[t] = s0 + s1;
      }
      __syncthreads();
      u = w1m / (scrB[m] + scrB[64 + m] + scrB[128 + m] + scrB[192 + m] + 1e-6f);
    }

    // row min/max partials over this wave's j-chunk
    {
      float mx = -3.402823466e38f, mn = 3.402823466e38f;
#pragma unroll
      for (int nn = 0; nn < 16; ++nn) {
        float g = u * kregT[nn] * lane_bcast(v, wq * 16 + nn);
        mx = fmaxf(mx, g);
        mn = fminf(mn, g);
      }
      scrA[t] = mx;
      scrB[t] = mn;
    }
    if (wq == 0) {
      uiL[l * 64 + m] = u;
      viL[l * 64 + m] = v;
    }
    __syncthreads();
    if (wq == 0) {
      float mx = fmaxf(fmaxf(scrA[m], scrA[64 + m]), fmaxf(scrA[128 + m], scrA[192 + m]));
      float mn = fminf(fminf(scrB[m], scrB[64 + m]), fminf(scrB[128 + m], scrB[192 + m]));
      rmL[l * 64 + m] = mn;
      riL[l * 64 + m] = 1.0f / (mx - mn + 1e-6f);
    }
    // next lambda's KM-build barrier protects rmL/riL reads
  }
  __syncthreads();

  // ---------------- G-phase: fused gd GEMV over all 8 lambdas ----------------
  // thread: gq = t>>3 owns 128 p's; k4 = t&7 owns float4 column group.
  int gq = t >> 3, k4 = t & 7;
  const float4* dp4 = (const float4*)dp;
  float4 acc[8];
#pragma unroll
  for (int l = 0; l < 8; ++l) acc[l] = make_float4(0.f, 0.f, 0.f, 0.f);

  for (int c = 0; c < 32; ++c) {
    int i = 2 * gq + (c >> 4);
    int j0 = (c & 15) * 4;
    int p0 = gq * 128 + c * 4;
    float msr[4], mf[4];
    float4 dpr[4];
    float w1i = w1s[i];
#pragma unroll
    for (int pp = 0; pp < 4; ++pp) {
      msr[pp] = Ms[i * 65 + j0 + pp];
      mf[pp] = (w1i > 0.f && w2s[j0 + pp] > 0.f) ? 1.0f : 0.0f;
      dpr[pp] = dp4[(p0 + pp) * 8 + k4];
    }
#pragma unroll
    for (int l = 0; l < 8; ++l) {
      float lam = c_LAM[l];
      float ul = uiL[l * 64 + i];
      float rm = rmL[l * 64 + i];
      float ri = riL[l * 64 + i];
#pragma unroll
      for (int pp = 0; pp < 4; ++pp) {
        float kv = mf[pp] * __expf(-lam * msr[pp]);
        float g = ul * kv * viL[l * 64 + j0 + pp];
        float w = (g - rm) * ri * msr[pp];
        acc[l].x += w * dpr[pp].x;
        acc[l].y += w * dpr[pp].y;
        acc[l].z += w * dpr[pp].z;
        acc[l].w += w * dpr[pp].w;
      }
    }
  }

  // reduction over gq (32 chunks) per lambda, double-buffered in KM region
  float* scrG = KM;  // 2 x 1056 floats, KM no longer needed
  {
    float* s0 = scrG;
    s0[(k4 * 4 + 0) * 33 + gq] = acc[0].x;
    s0[(k4 * 4 + 1) * 33 + gq] = acc[0].y;
    s0[(k4 * 4 + 2) * 33 + gq] = acc[0].z;
    s0[(k4 * 4 + 3) * 33 + gq] = acc[0].w;
  }
  __syncthreads();
  for (int l = 1; l <= 8; ++l) {
    if (l < 8) {
      float* sb = scrG + (l & 1) * 1056;
      sb[(k4 * 4 + 0) * 33 + gq] = acc[l].x;
      sb[(k4 * 4 + 1) * 33 + gq] = acc[l].y;
      sb[(k4 * 4 + 2) * 33 + gq] = acc[l].z;
      sb[(k4 * 4 + 3) * 33 + gq] = acc[l].w;
    }
    if (t < 32) {
      const float* sp = scrG + ((l - 1) & 1) * 1056 + t * 33;
      float s = 0.f;
#pragma unroll
      for (int g2 = 0; g2 < 32; ++g2) s += sp[g2];
      gall[(size_t)(((l - 1) * 32 + b) * 30 + d) * 32 + t] = s;
    }
    __syncthreads();
  }
}

// =====================================================================
// Final: coeff = softmax_l(gall @ wl), embed, fc1 (4 lanes/output), fc2, kl
// =====================================================================
__global__ __launch_bounds__(256) void final_kernel(
    const float* __restrict__ gall, const float* __restrict__ wl,
    const float* __restrict__ fc1w, const float* __restrict__ fc1b,
    const float* __restrict__ fc2w, const float* __restrict__ fc2b,
    const float* __restrict__ klpart, float* __restrict__ out) {
  int b = blockIdx.x, t = threadIdx.x;
  __shared__ __align__(16) float4 embedL4[240];
  __shared__ float sred[32];
  __shared__ float coeff[8];
  __shared__ float hL[64];
  float part[8] = {0, 0, 0, 0, 0, 0, 0, 0};
  for (int j = t; j < 960; j += 256) {
    float w = wl[j];
#pragma unroll
    for (int l = 0; l < 8; ++l) part[l] += gall[l * 30720 + b * 960 + j] * w;
  }
#pragma unroll
  for (int off = 32; off > 0; off >>= 1) {
#pragma unroll
    for (int l = 0; l < 8; ++l) part[l] += __shfl_down(part[l], off, 64);
  }
  int wv = t >> 6, lane = t & 63;
  if (lane == 0) {
#pragma unroll
    for (int l = 0; l < 8; ++l) sred[l * 4 + wv] = part[l];
  }
  __syncthreads();
  if (t == 0) {
    float s[8], mx = -3.402823466e38f;
#pragma unroll
    for (int l = 0; l < 8; ++l) {
      s[l] = sred[l * 4] + sred[l * 4 + 1] + sred[l * 4 + 2] + sred[l * 4 + 3];
      mx = fmaxf(mx, s[l]);
    }
    float se = 0.f;
#pragma unroll
    for (int l = 0; l < 8; ++l) {
      s[l] = expf(s[l] - mx);
      se += s[l];
    }
#pragma unroll
    for (int l = 0; l < 8; ++l) coeff[l] = s[l] / se;
  }
  __syncthreads();
  for (int j = t; j < 960; j += 256) {
    float e = 0.f;
#pragma unroll
    for (int l = 0; l < 8; ++l) e += gall[l * 30720 + b * 960 + j] * coeff[l];
    ((float*)embedL4)[j] = e;
  }
  __syncthreads();
  // fc1: o = t>>2, 4 lanes per output, coalesced float4 weight reads
  {
    int o = t >> 2, l4 = t & 3;
    const float4* w4 = (const float4*)fc1w;
    float hp = 0.f;
#pragma unroll 4
    for (int k = 0; k < 60; ++k) {
      int jf = l4 + 4 * k;
      float4 wv4 = w4[o * 240 + jf];
      float4 ev = embedL4[jf];
      hp += wv4.x * ev.x + wv4.y * ev.y + wv4.z * ev.z + wv4.w * ev.w;
    }
    hp += __shfl_down(hp, 2, 64);
    hp += __shfl_down(hp, 1, 64);
    if (l4 == 0) hL[o] = hp + fc1b[o];
  }
  __syncthreads();
  if (t < 3) {
    float o = fc2b[t];
#pragma unroll
    for (int j = 0; j < 64; ++j) o += hL[j] * fc2w[t * 64 + j];
    out[b * 3 + t] = o;
  }
  if (b == 0 && t == 4) {
    float kl = 0.f;
    for (int dd = 0; dd < 30; ++dd) kl += klpart[dd];
    out[96] = kl;
  }
}

// =====================================================================
extern "C" void kernel_launch(void* const* d_in, const int* in_sizes, int n_in,
                              void* d_out, int out_size, void* d_ws,
                              size_t ws_size, hipStream_t stream) {
  (void)in_sizes; (void)n_in; (void)out_size; (void)ws_size;
  const float* x = (const float*)d_in[0];
  const float* adj = (const float*)d_in[1];
  const int* num_node = (const int*)d_in[2];
  const float* dict_feat = (const float*)d_in[3];
  const float* dict_adj = (const float*)d_in[4];
  const int* dict_nnode = (const int*)d_in[5];
  const float* eW1 = (const float*)d_in[6];
  const float* eb1 = (const float*)d_in[7];
  const float* eW2 = (const float*)d_in[8];
  const float* eb2 = (const float*)d_in[9];
  const float* eW3 = (const float*)d_in[10];
  const float* eb3 = (const float*)d_in[11];
  const float* dW1 = (const float*)d_in[12];
  const float* db1 = (const float*)d_in[13];
  const float* dW2 = (const float*)d_in[14];
  const float* db2 = (const float*)d_in[15];
  const float* dW3 = (const float*)d_in[16];
  const float* db3 = (const float*)d_in[17];
  const float* mlp_w = (const float*)d_in[18];
  const float* mlp_b = (const float*)d_in[19];
  const float* mlp2_w = (const float*)d_in[20];
  const float* mlp2_b = (const float*)d_in[21];
  const float* dist_para = (const float*)d_in[22];
  const float* weight_lamda = (const float*)d_in[23];
  const float* fc1_w = (const float*)d_in[24];
  const float* fc1_b = (const float*)d_in[25];
  const float* fc2_w = (const float*)d_in[26];
  const float* fc2_b = (const float*)d_in[27];

  float* ws = (float*)d_ws;
  float* xe = ws + OFF_XE;
  float* de = ws + OFF_DE;
  float* dsb = ws + OFF_DS;
  float* x2b = ws + OFF_X2;
  float* y2b = ws + OFF_Y2;
  float* ywb = ws + OFF_YW;
  float* klb = ws + OFF_KL;
  float* gall = ws + OFF_GALL;

  gcn_kernel<<<62, 256, 0, stream>>>(x, adj, eW1, eb1, eW2, eb2, eW3, eb3,
                                     dict_feat, dict_adj, dW1, db1, dW2, db2,
                                     dW3, db3, mlp_w, mlp2_w, xe, de, x2b, ywb);
  attn_kernel<<<30, 256, 0, stream>>>(de, ywb, mlp_b, mlp2_w, mlp2_b, dsb,
                                      y2b, klb);
  sink_kernel<<<960, 256, 0, stream>>>(xe, dsb, x2b, y2b, num_node,
                                       dict_nnode, dist_para, gall);
  final_kernel<<<32, 256, 0, stream>>>(gall, weight_lamda, fc1_w, fc1_b, fc2_w,
                                       fc2_b, klb, (float*)d_out);
}

// Round 6
// 353.407 us; speedup vs baseline: 1.3536x; 1.1164x over previous
//
#include <hip/hip_runtime.h>
#include <hip/hip_bf16.h>

// Problem constants
// B=32, N=64, D=30, ND=64, F0=64, H1=128, H2=64, H3=32, L=8, SINK_K=10
// LAMDA = {0.01,0.1,0.5,1.0,3.0,5.0,10.0,20.0}, P0=0.5, EPS=1e-6

__device__ __constant__ float c_LAM[8] = {0.01f, 0.1f, 0.5f, 1.0f, 3.0f, 5.0f, 10.0f, 20.0f};

// ---------------- workspace layout (float offsets) ----------------
constexpr int OFF_XE   = 0;         // 32*64*32 = 65536
constexpr int OFF_DE   = 65536;     // 30*64*32 = 61440
constexpr int OFF_DS   = 126976;    // 30*64*32 = 61440
constexpr int OFF_X2   = 188416;    // 2048
constexpr int OFF_Y2   = 190464;    // 1920
constexpr int OFF_YW   = 192384;    // 32*32 = 1024
constexpr int OFF_KL   = 193408;    // 64
constexpr int OFF_GALL = 193472;    // 8*32*960 = 245760

// wave-uniform broadcast of another lane's value (idx must be wave-uniform)
__device__ __forceinline__ float lane_bcast(float v, int lane) {
  return __int_as_float(__builtin_amdgcn_readlane(__float_as_int(v), lane));
}
// fp32 -> bf16 bits (RNE)
__device__ __forceinline__ unsigned bf16_bits(float f) {
  unsigned u = __float_as_uint(f);
  return (u + 0x7fffu + ((u >> 16) & 1u)) >> 16;
}
__device__ __forceinline__ float bf16_val(unsigned short h) {
  return __uint_as_float(((unsigned)h) << 16);
}

// =====================================================================
// GCN encoder: 512 threads, one block per graph (0..31 x-enc, 32..61 dict)
// =====================================================================
template <int K, int J, int NT>
__device__ __forceinline__ void mm64(const float* __restrict__ A, int lda,
                                     const float* __restrict__ W,
                                     float* __restrict__ C,
                                     const float* __restrict__ bias,
                                     bool do_relu, int t) {
  constexpr int JT = J >> 2;
  constexpr int TILES = 16 * JT;
  for (int task = t; task < TILES; task += NT) {
    int i4 = task / JT;
    int j4 = task - i4 * JT;
    const float* a0 = A + (i4 * 4 + 0) * lda;
    const float* a1 = a0 + lda;
    const float* a2 = a1 + lda;
    const float* a3 = a2 + lda;
    float acc[4][4];
#pragma unroll
    for (int r = 0; r < 4; ++r)
#pragma unroll
      for (int c = 0; c < 4; ++c) acc[r][c] = 0.0f;
    const float* wp = W + j4 * 4;
#pragma unroll 8
    for (int k = 0; k < K; ++k) {
      float4 w = *(const float4*)(wp + k * J);
      float v0 = a0[k], v1 = a1[k], v2 = a2[k], v3 = a3[k];
      acc[0][0] += v0 * w.x; acc[0][1] += v0 * w.y; acc[0][2] += v0 * w.z; acc[0][3] += v0 * w.w;
      acc[1][0] += v1 * w.x; acc[1][1] += v1 * w.y; acc[1][2] += v1 * w.z; acc[1][3] += v1 * w.w;
      acc[2][0] += v2 * w.x; acc[2][1] += v2 * w.y; acc[2][2] += v2 * w.z; acc[2][3] += v2 * w.w;
      acc[3][0] += v3 * w.x; acc[3][1] += v3 * w.y; acc[3][2] += v3 * w.z; acc[3][3] += v3 * w.w;
    }
    float4 bv = make_float4(0.f, 0.f, 0.f, 0.f);
    if (bias) bv = *(const float4*)(bias + j4 * 4);
#pragma unroll
    for (int r = 0; r < 4; ++r) {
      float o0 = acc[r][0] + bv.x, o1 = acc[r][1] + bv.y;
      float o2 = acc[r][2] + bv.z, o3 = acc[r][3] + bv.w;
      if (do_relu) {
        o0 = fmaxf(o0, 0.f); o1 = fmaxf(o1, 0.f);
        o2 = fmaxf(o2, 0.f); o3 = fmaxf(o3, 0.f);
      }
      *(float4*)(C + (i4 * 4 + r) * J + j4 * 4) = make_float4(o0, o1, o2, o3);
    }
  }
}

__global__ __launch_bounds__(512) void gcn_kernel(
    const float* __restrict__ x, const float* __restrict__ adj,
    const float* __restrict__ eW1, const float* __restrict__ eb1,
    const float* __restrict__ eW2, const float* __restrict__ eb2,
    const float* __restrict__ eW3, const float* __restrict__ eb3,
    const float* __restrict__ dx, const float* __restrict__ dadj,
    const float* __restrict__ dW1, const float* __restrict__ db1,
    const float* __restrict__ dW2, const float* __restrict__ db2,
    const float* __restrict__ dW3, const float* __restrict__ db3,
    const float* __restrict__ mlp_w, const float* __restrict__ mlp2_w,
    float* __restrict__ xe, float* __restrict__ de,
    float* __restrict__ x2b, float* __restrict__ yw) {
  __shared__ float As[64 * 65];
  __shared__ float Aa[64 * 65];
  __shared__ __align__(16) float C0[64 * 128];
  __shared__ __align__(16) float C1[64 * 128];
  int t = threadIdx.x;
  const float *src, *ad, *W1, *b1, *W2, *b2, *W3, *b3;
  float* outp;
  bool is_x = (blockIdx.x < 32);
  int g;
  if (is_x) {
    g = blockIdx.x;
    src = x + g * 4096; ad = adj + g * 4096;
    W1 = eW1; b1 = eb1; W2 = eW2; b2 = eb2; W3 = eW3; b3 = eb3;
    outp = xe + g * 2048;
  } else {
    g = blockIdx.x - 32;
    src = dx + g * 4096; ad = dadj + g * 4096;
    W1 = dW1; b1 = db1; W2 = dW2; b2 = db2; W3 = dW3; b3 = db3;
    outp = de + g * 2048;
  }
  {
    const float4* s4 = (const float4*)src;
    const float4* a4 = (const float4*)ad;
    for (int idx = t; idx < 1024; idx += 512) {
      int r = idx >> 4, c = (idx & 15) * 4;
      float4 v = s4[idx];
      As[r * 65 + c] = v.x; As[r * 65 + c + 1] = v.y;
      As[r * 65 + c + 2] = v.z; As[r * 65 + c + 3] = v.w;
      float4 w = a4[idx];
      Aa[r * 65 + c] = w.x; Aa[r * 65 + c + 1] = w.y;
      Aa[r * 65 + c + 2] = w.z; Aa[r * 65 + c + 3] = w.w;
    }
  }
  __syncthreads();
  mm64<64, 128, 512>(As, 65, W1, C1, nullptr, false, t);
  __syncthreads();
  mm64<64, 128, 512>(Aa, 65, C1, C0, b1, true, t);
  __syncthreads();
  mm64<128, 64, 512>(C0, 128, W2, C1, nullptr, false, t);
  __syncthreads();
  mm64<64, 64, 512>(Aa, 65, C1, C0, b2, true, t);
  __syncthreads();
  mm64<64, 32, 512>(C0, 64, W3, C1, nullptr, false, t);
  __syncthreads();
  mm64<64, 32, 512>(Aa, 65, C1, outp, b3, false, t);
  __syncthreads();
  if (is_x) {
    if (t < 64) {
      const float* r = outp + t * 32;
      float s = 0.f;
#pragma unroll
      for (int f = 0; f < 32; ++f) s += r[f] * r[f];
      x2b[g * 64 + t] = s;
    } else if (t < 96) {
      int f = t - 64;
      float s = 0.f, sb = 0.f;
      for (int n = 0; n < 64; ++n) {
        float v = outp[n * 32 + f];
        s += v * v;
        sb += v * mlp_w[n];
      }
      yw[g * 32 + f] = mlp2_w[g] * sb / (sqrtf(s) + 1e-12f);
    }
  }
}

// =====================================================================
// JAX threefry2x32, key = (0, 42)
// =====================================================================
__device__ __forceinline__ unsigned rotl32(unsigned v, int s) {
  return (v << s) | (v >> (32 - s));
}
__device__ __forceinline__ void threefry42(unsigned x0, unsigned x1,
                                           unsigned& o0, unsigned& o1) {
  const unsigned ks0 = 0u, ks1 = 42u, ks2 = 0x1BD11BDAu ^ 0u ^ 42u;
  unsigned ks[3] = {ks0, ks1, ks2};
  x0 += ks[0];
  x1 += ks[1];
  const int R[2][4] = {{13, 15, 26, 6}, {17, 29, 16, 24}};
#pragma unroll
  for (int r = 0; r < 5; ++r) {
    const int* rr = R[r & 1];
#pragma unroll
    for (int i = 0; i < 4; ++i) {
      x0 += x1;
      x1 = rotl32(x1, rr[i]);
      x1 ^= x0;
    }
    x0 += ks[(r + 1) % 3];
    x1 += ks[(r + 2) % 3] + (unsigned)(r + 1);
  }
  o0 = x0;
  o1 = x1;
}

// =====================================================================
__global__ __launch_bounds__(256) void attn_kernel(
    const float* __restrict__ de, const float* __restrict__ yw,
    const float* __restrict__ mlp_b, const float* __restrict__ mlp2_w,
    const float* __restrict__ mlp2_b, float* __restrict__ dsamp,
    float* __restrict__ y2, float* __restrict__ klpart) {
  int d = blockIdx.x, t = threadIdx.x;
  __shared__ float zs[32], dns[32], c0s[1];
  if (t < 32) {
    float zz = 0.f;
    for (int b = 0; b < 32; ++b) zz += yw[b * 32 + t];
    zs[t] = zz;
  } else if (t < 64) {
    int f = t - 32;
    float s = 0.f;
    for (int n = 0; n < 64; ++n) {
      float v = de[d * 2048 + n * 32 + f];
      s += v * v;
    }
    dns[f] = sqrtf(s) + 1e-12f;
  } else if (t == 64) {
    float sm2 = 0.f;
    for (int b = 0; b < 32; ++b) sm2 += mlp2_w[b];
    c0s[0] = mlp_b[0] * sm2 + mlp2_b[0];
  }
  __syncthreads();
  if (t < 64) {
    int m = t;
    const float* row = de + d * 2048 + m * 32;
    float logit = c0s[0], s2 = 0.f;
#pragma unroll 8
    for (int f = 0; f < 32; ++f) {
      float v = row[f];
      logit += (v / dns[f]) * zs[f];
      s2 += v * v;
    }
    float attn = 1.0f / (1.0f + expf(-logit));
    int e = d * 64 + m;
    unsigned o0, o1, bits;
    if (e < 960) {
      threefry42((unsigned)e, (unsigned)(960 + e), o0, o1);
      bits = o0;
    } else {
      threefry42((unsigned)(e - 960), (unsigned)e, o0, o1);
      bits = o1;
    }
    float u = __uint_as_float((bits >> 9) | 0x3f800000u) - 1.0f;
    u = fmaxf(u, 0.0f);
    float bern = (u < attn) ? 1.0f : 0.0f;
    float* dr = dsamp + d * 2048 + m * 32;
#pragma unroll 8
    for (int f = 0; f < 32; ++f) dr[f] = bern * row[f];
    y2[e] = bern * s2;
    float klt = attn * logf(2.0f * attn) + (1.0f - attn) * logf(2.0f * (1.0f - attn));
#pragma unroll
    for (int off = 32; off > 0; off >>= 1) klt += __shfl_down(klt, off, 64);
    if (m == 0) klpart[d] = klt;
  }
}

// =====================================================================
// Sinkhorn + gd, wave-per-lambda. Grid 1920 = (b,d) x 2 halves; 256 thr.
// Wave w handles lambda = half*4+w fully intra-wave (no barriers in the
// 10 iterations): u,v in lane registers, K stored as bf16 DEVIATION
// Kd = exp(-lam*M)-1 (masked = -1), so K^T u = sum(u) + Kd^T u.
// G-phase: exp-free, dp read once per block, per-thread (2 rows x 8 cols).
// =====================================================================
__global__ __launch_bounds__(256) void sink_kernel(
    const float* __restrict__ xe, const float* __restrict__ ds,
    const float* __restrict__ x2g, const float* __restrict__ y2g,
    const int* __restrict__ num_node, const int* __restrict__ dict_nnode,
    const float* __restrict__ dp, float* __restrict__ gall) {
  __shared__ unsigned short KdL[4 * 64 * 66];  // 33792 B (aliases staging)
  __shared__ unsigned short Msb[64 * 66];      // 8448 B
  __shared__ float uL[4][64], vL[4][64], rmL[4][64], riL[4][64];
  __shared__ float w1s[64], w2s[64], x2s[64], y2s[64];
  __shared__ __align__(16) float Gred[4 * 8 * 4 * 4];  // [wave][k4][l][c]

  int t = threadIdx.x;
  int m = t & 63;
  int wv = t >> 6;
  int bd = blockIdx.x >> 1;
  int half = blockIdx.x & 1;
  int b = bd / 30;
  int d = bd - b * 30;

  // ---- stage xe/ds (fp32) into KdL alias region
  float* XEp = (float*)KdL;        // 64*33 floats
  float* DSp = XEp + 2112;         // 64*33 floats (16896 B total <= 33792)
  {
    const float* xsrc = xe + b * 2048;
    const float* dsrc = ds + d * 2048;
    for (int i = t; i < 2048; i += 256) {
      int r = i >> 5, c = i & 31;
      XEp[r * 33 + c] = xsrc[i];
      DSp[r * 33 + c] = dsrc[i];
    }
  }
  if (t < 64) {
    int nn = num_node[b], dnn = dict_nnode[d];
    w1s[t] = (t < nn) ? 1.0f / (float)nn : 0.0f;
    w2s[t] = (t < dnn) ? 1.0f / (float)dnn : 0.0f;
    x2s[t] = x2g[b * 64 + t];
    y2s[t] = y2g[d * 64 + t];
  }
  __syncthreads();

  // ---- M build -> bf16 pairs, stride 66
  unsigned* Msb32 = (unsigned*)Msb;
#pragma unroll
  for (int e = 0; e < 8; ++e) {
    int idx = e * 256 + t;            // 2048 pairs
    int i = idx >> 5, j0 = (idx & 31) * 2;
    const float* xr = XEp + i * 33;
    const float* d0 = DSp + j0 * 33;
    const float* d1 = d0 + 33;
    float a0 = 0.f, a1 = 0.f;
#pragma unroll
    for (int f = 0; f < 32; ++f) {
      float xv = xr[f];
      a0 = fmaf(xv, d0[f], a0);
      a1 = fmaf(xv, d1[f], a1);
    }
    float m0 = x2s[i] + y2s[j0] - 2.0f * a0;
    float m1 = x2s[i] + y2s[j0 + 1] - 2.0f * a1;
    Msb32[i * 33 + (j0 >> 1)] = bf16_bits(m0) | (bf16_bits(m1) << 16);
  }
  __syncthreads();  // Ms ready; KdL region free

  // ---- K-build: wave wv builds lambda = half*4+wv; lane m builds row m.
  int l_my = half * 4 + wv;
  float lam = c_LAM[l_my];
  {
    bool rv = (w1s[m] > 0.f);
    unsigned* krow = (unsigned*)(KdL + wv * 4224);  // row m at u32 idx m*33
#pragma unroll 8
    for (int jp = 0; jp < 32; ++jp) {
      int j0 = 2 * jp;
      unsigned mp = Msb32[m * 33 + jp];
      float mv0 = __uint_as_float(mp << 16);
      float mv1 = __uint_as_float(mp & 0xffff0000u);
      float k0 = (rv && w2s[j0] > 0.f) ? (__expf(-lam * mv0) - 1.0f) : -1.0f;
      float k1 = (rv && w2s[j0 + 1] > 0.f) ? (__expf(-lam * mv1) - 1.0f) : -1.0f;
      krow[m * 33 + jp] = bf16_bits(k0) | (bf16_bits(k1) << 16);
    }
  }
  // no barrier: wave reads only its own lambda's rows (written by itself)

  // ---- Sinkhorn iterations (intra-wave only)
  {
    const unsigned short* Kw = KdL + wv * 4224;
    float w1m = w1s[m], w2m = w2s[m];
    float u = 1.0f, v = 0.0f;
    for (int it = 0; it < 10; ++it) {
      float Su = u;
#pragma unroll
      for (int off = 1; off < 64; off <<= 1) Su += __shfl_xor(Su, off, 64);
      float tv = 0.f;
#pragma unroll
      for (int i = 0; i < 64; ++i) {
        float kf = bf16_val(Kw[i * 66 + m]);
        tv = fmaf(kf, lane_bcast(u, i), tv);
      }
      v = w2m / (Su + tv + 1e-6f);
      float Sv = v;
#pragma unroll
      for (int off = 1; off < 64; off <<= 1) Sv += __shfl_xor(Sv, off, 64);
      float tu = 0.f;
#pragma unroll
      for (int j = 0; j < 64; ++j) {
        float kf = bf16_val(Kw[m * 66 + j]);
        tu = fmaf(kf, lane_bcast(v, j), tu);
      }
      u = w1m / (Sv + tu + 1e-6f);
    }
    // row min/max of G = u*(1+Kd)*v
    float mx = -3.402823466e38f, mn = 3.402823466e38f;
#pragma unroll
    for (int j = 0; j < 64; ++j) {
      float kf = bf16_val(Kw[m * 66 + j]);
      float g = u * (1.0f + kf) * lane_bcast(v, j);
      mx = fmaxf(mx, g);
      mn = fminf(mn, g);
    }
    uL[wv][m] = u;
    vL[wv][m] = v;
    rmL[wv][m] = mn;
    riL[wv][m] = 1.0f / (mx - mn + 1e-6f);
  }
  __syncthreads();

  // ---- G-phase: thread (gq = t>>3 in [0,32), k4 = t&7) owns rows 2gq,2gq+1
  int gq = t >> 3, k4 = t & 7;
  const float4* dp4 = (const float4*)dp;
  float4 acc[4];
#pragma unroll
  for (int l = 0; l < 4; ++l) acc[l] = make_float4(0.f, 0.f, 0.f, 0.f);

#pragma unroll
  for (int ii = 0; ii < 2; ++ii) {
    int i = gq * 2 + ii;
    float ua[4], rma[4], ria[4];
#pragma unroll
    for (int l = 0; l < 4; ++l) {
      ua[l] = uL[l][i];
      rma[l] = rmL[l][i];
      ria[l] = riL[l][i];
    }
    for (int j = 0; j < 64; ++j) {
      int p = i * 64 + j;
      float4 dv = dp4[p * 8 + k4];
      float mv = bf16_val(Msb[i * 66 + j]);
#pragma unroll
      for (int l = 0; l < 4; ++l) {
        float kf = bf16_val(KdL[l * 4224 + i * 66 + j]);
        float g = ua[l] * (1.0f + kf) * vL[l][j];
        float w = (g - rma[l]) * ria[l] * mv;
        acc[l].x = fmaf(w, dv.x, acc[l].x);
        acc[l].y = fmaf(w, dv.y, acc[l].y);
        acc[l].z = fmaf(w, dv.z, acc[l].z);
        acc[l].w = fmaf(w, dv.w, acc[l].w);
      }
    }
  }
  // in-wave reduce over the 8 gq-subgroups (lane stride 8)
#pragma unroll
  for (int off = 32; off >= 8; off >>= 1) {
#pragma unroll
    for (int l = 0; l < 4; ++l) {
      acc[l].x += __shfl_down(acc[l].x, off, 64);
      acc[l].y += __shfl_down(acc[l].y, off, 64);
      acc[l].z += __shfl_down(acc[l].z, off, 64);
      acc[l].w += __shfl_down(acc[l].w, off, 64);
    }
  }
  if ((t & 63) < 8) {
#pragma unroll
    for (int l = 0; l < 4; ++l)
      *(float4*)&Gred[((wv * 8 + k4) * 4 + l) * 4] = acc[l];
  }
  __syncthreads();
  if (t < 128) {
    int l = t >> 5, k = t & 31;
    int kq = k >> 2, kc = k & 3;
    float s = 0.f;
#pragma unroll
    for (int w = 0; w < 4; ++w) s += Gred[((w * 8 + kq) * 4 + l) * 4 + kc];
    int lg = half * 4 + l;
    gall[(size_t)((lg * 32 + b) * 30 + d) * 32 + k] = s;
  }
}

// =====================================================================
__global__ __launch_bounds__(256) void final_kernel(
    const float* __restrict__ gall, const float* __restrict__ wl,
    const float* __restrict__ fc1w, const float* __restrict__ fc1b,
    const float* __restrict__ fc2w, const float* __restrict__ fc2b,
    const float* __restrict__ klpart, float* __restrict__ out) {
  int b = blockIdx.x, t = threadIdx.x;
  __shared__ __align__(16) float4 embedL4[240];
  __shared__ float sred[32];
  __shared__ float coeff[8];
  __shared__ float hL[64];
  float part[8] = {0, 0, 0, 0, 0, 0, 0, 0};
  for (int j = t; j < 960; j += 256) {
    float w = wl[j];
#pragma unroll
    for (int l = 0; l < 8; ++l) part[l] += gall[l * 30720 + b * 960 + j] * w;
  }
#pragma unroll
  for (int off = 32; off > 0; off >>= 1) {
#pragma unroll
    for (int l = 0; l < 8; ++l) part[l] += __shfl_down(part[l], off, 64);
  }
  int wv = t >> 6, lane = t & 63;
  if (lane == 0) {
#pragma unroll
    for (int l = 0; l < 8; ++l) sred[l * 4 + wv] = part[l];
  }
  __syncthreads();
  if (t == 0) {
    float s[8], mx = -3.402823466e38f;
#pragma unroll
    for (int l = 0; l < 8; ++l) {
      s[l] = sred[l * 4] + sred[l * 4 + 1] + sred[l * 4 + 2] + sred[l * 4 + 3];
      mx = fmaxf(mx, s[l]);
    }
    float se = 0.f;
#pragma unroll
    for (int l = 0; l < 8; ++l) {
      s[l] = expf(s[l] - mx);
      se += s[l];
    }
#pragma unroll
    for (int l = 0; l < 8; ++l) coeff[l] = s[l] / se;
  }
  __syncthreads();
  for (int j = t; j < 960; j += 256) {
    float e = 0.f;
#pragma unroll
    for (int l = 0; l < 8; ++l) e += gall[l * 30720 + b * 960 + j] * coeff[l];
    ((float*)embedL4)[j] = e;
  }
  __syncthreads();
  {
    int o = t >> 2, l4 = t & 3;
    const float4* w4 = (const float4*)fc1w;
    float hp = 0.f;
#pragma unroll 4
    for (int k = 0; k < 60; ++k) {
      int jf = l4 + 4 * k;
      float4 wv4 = w4[o * 240 + jf];
      float4 ev = embedL4[jf];
      hp += wv4.x * ev.x + wv4.y * ev.y + wv4.z * ev.z + wv4.w * ev.w;
    }
    hp += __shfl_down(hp, 2, 64);
    hp += __shfl_down(hp, 1, 64);
    if (l4 == 0) hL[o] = hp + fc1b[o];
  }
  __syncthreads();
  if (t < 3) {
    float o = fc2b[t];
#pragma unroll
    for (int j = 0; j < 64; ++j) o += hL[j] * fc2w[t * 64 + j];
    out[b * 3 + t] = o;
  }
  if (b == 0 && t == 4) {
    float kl = 0.f;
    for (int dd = 0; dd < 30; ++dd) kl += klpart[dd];
    out[96] = kl;
  }
}

// =====================================================================
extern "C" void kernel_launch(void* const* d_in, const int* in_sizes, int n_in,
                              void* d_out, int out_size, void* d_ws,
                              size_t ws_size, hipStream_t stream) {
  (void)in_sizes; (void)n_in; (void)out_size; (void)ws_size;
  const float* x = (const float*)d_in[0];
  const float* adj = (const float*)d_in[1];
  const int* num_node = (const int*)d_in[2];
  const float* dict_feat = (const float*)d_in[3];
  const float* dict_adj = (const float*)d_in[4];
  const int* dict_nnode = (const int*)d_in[5];
  const float* eW1 = (const float*)d_in[6];
  const float* eb1 = (const float*)d_in[7];
  const float* eW2 = (const float*)d_in[8];
  const float* eb2 = (const float*)d_in[9];
  const float* eW3 = (const float*)d_in[10];
  const float* eb3 = (const float*)d_in[11];
  const float* dW1 = (const float*)d_in[12];
  const float* db1 = (const float*)d_in[13];
  const float* dW2 = (const float*)d_in[14];
  const float* db2 = (const float*)d_in[15];
  const float* dW3 = (const float*)d_in[16];
  const float* db3 = (const float*)d_in[17];
  const float* mlp_w = (const float*)d_in[18];
  const float* mlp_b = (const float*)d_in[19];
  const float* mlp2_w = (const float*)d_in[20];
  const float* mlp2_b = (const float*)d_in[21];
  const float* dist_para = (const float*)d_in[22];
  const float* weight_lamda = (const float*)d_in[23];
  const float* fc1_w = (const float*)d_in[24];
  const float* fc1_b = (const float*)d_in[25];
  const float* fc2_w = (const float*)d_in[26];
  const float* fc2_b = (const float*)d_in[27];

  float* ws = (float*)d_ws;
  float* xe = ws + OFF_XE;
  float* de = ws + OFF_DE;
  float* dsb = ws + OFF_DS;
  float* x2b = ws + OFF_X2;
  float* y2b = ws + OFF_Y2;
  float* ywb = ws + OFF_YW;
  float* klb = ws + OFF_KL;
  float* gall = ws + OFF_GALL;

  gcn_kernel<<<62, 512, 0, stream>>>(x, adj, eW1, eb1, eW2, eb2, eW3, eb3,
                                     dict_feat, dict_adj, dW1, db1, dW2, db2,
                                     dW3, db3, mlp_w, mlp2_w, xe, de, x2b, ywb);
  attn_kernel<<<30, 256, 0, stream>>>(de, ywb, mlp_b, mlp2_w, mlp2_b, dsb,
                                      y2b, klb);
  sink_kernel<<<1920, 256, 0, stream>>>(xe, dsb, x2b, y2b, num_node,
                                        dict_nnode, dist_para, gall);
  final_kernel<<<32, 256, 0, stream>>>(gall, weight_lamda, fc1_w, fc1_b, fc2_w,
                                       fc2_b, klb, (float*)d_out);
}

// Round 7
// 281.164 us; speedup vs baseline: 1.7014x; 1.2569x over previous
//
#include <hip/hip_runtime.h>
#include <hip/hip_bf16.h>

// Problem constants
// B=32, N=64, D=30, ND=64, F0=64, H1=128, H2=64, H3=32, L=8, SINK_K=10
// LAMDA = {0.01,0.1,0.5,1.0,3.0,5.0,10.0,20.0}, P0=0.5, EPS=1e-6

__device__ __constant__ float c_LAM[8] = {0.01f, 0.1f, 0.5f, 1.0f, 3.0f, 5.0f, 10.0f, 20.0f};

// ---------------- workspace layout (float offsets) ----------------
constexpr int OFF_XE   = 0;         // 32*64*32 = 65536
constexpr int OFF_DE   = 65536;     // 30*64*32 = 61440
constexpr int OFF_DS   = 126976;    // 30*64*32 = 61440
constexpr int OFF_X2   = 188416;    // 2048
constexpr int OFF_Y2   = 190464;    // 1920
constexpr int OFF_YW   = 192384;    // 32*32 = 1024
constexpr int OFF_KL   = 193408;    // 64
constexpr int OFF_GALL = 193472;    // 8*32*960 = 245760

// wave-uniform broadcast of another lane's value (idx must be wave-uniform)
__device__ __forceinline__ float lane_bcast(float v, int lane) {
  return __int_as_float(__builtin_amdgcn_readlane(__float_as_int(v), lane));
}
// fp32 -> bf16 bits (RNE)
__device__ __forceinline__ unsigned bf16_bits(float f) {
  unsigned u = __float_as_uint(f);
  return (u + 0x7fffu + ((u >> 16) & 1u)) >> 16;
}
__device__ __forceinline__ float bf16_val(unsigned short h) {
  return __uint_as_float(((unsigned)h) << 16);
}
__device__ __forceinline__ float bflo(unsigned p) { return __uint_as_float(p << 16); }
__device__ __forceinline__ float bfhi(unsigned p) { return __uint_as_float(p & 0xffff0000u); }

// =====================================================================
// GCN encoder: 512 threads, one block per graph (0..31 x-enc, 32..61 dict)
// =====================================================================
template <int K, int J, int NT>
__device__ __forceinline__ void mm64(const float* __restrict__ A, int lda,
                                     const float* __restrict__ W,
                                     float* __restrict__ C,
                                     const float* __restrict__ bias,
                                     bool do_relu, int t) {
  constexpr int JT = J >> 2;
  constexpr int TILES = 16 * JT;
  for (int task = t; task < TILES; task += NT) {
    int i4 = task / JT;
    int j4 = task - i4 * JT;
    const float* a0 = A + (i4 * 4 + 0) * lda;
    const float* a1 = a0 + lda;
    const float* a2 = a1 + lda;
    const float* a3 = a2 + lda;
    float acc[4][4];
#pragma unroll
    for (int r = 0; r < 4; ++r)
#pragma unroll
      for (int c = 0; c < 4; ++c) acc[r][c] = 0.0f;
    const float* wp = W + j4 * 4;
#pragma unroll 8
    for (int k = 0; k < K; ++k) {
      float4 w = *(const float4*)(wp + k * J);
      float v0 = a0[k], v1 = a1[k], v2 = a2[k], v3 = a3[k];
      acc[0][0] += v0 * w.x; acc[0][1] += v0 * w.y; acc[0][2] += v0 * w.z; acc[0][3] += v0 * w.w;
      acc[1][0] += v1 * w.x; acc[1][1] += v1 * w.y; acc[1][2] += v1 * w.z; acc[1][3] += v1 * w.w;
      acc[2][0] += v2 * w.x; acc[2][1] += v2 * w.y; acc[2][2] += v2 * w.z; acc[2][3] += v2 * w.w;
      acc[3][0] += v3 * w.x; acc[3][1] += v3 * w.y; acc[3][2] += v3 * w.z; acc[3][3] += v3 * w.w;
    }
    float4 bv = make_float4(0.f, 0.f, 0.f, 0.f);
    if (bias) bv = *(const float4*)(bias + j4 * 4);
#pragma unroll
    for (int r = 0; r < 4; ++r) {
      float o0 = acc[r][0] + bv.x, o1 = acc[r][1] + bv.y;
      float o2 = acc[r][2] + bv.z, o3 = acc[r][3] + bv.w;
      if (do_relu) {
        o0 = fmaxf(o0, 0.f); o1 = fmaxf(o1, 0.f);
        o2 = fmaxf(o2, 0.f); o3 = fmaxf(o3, 0.f);
      }
      *(float4*)(C + (i4 * 4 + r) * J + j4 * 4) = make_float4(o0, o1, o2, o3);
    }
  }
}

__global__ __launch_bounds__(512) void gcn_kernel(
    const float* __restrict__ x, const float* __restrict__ adj,
    const float* __restrict__ eW1, const float* __restrict__ eb1,
    const float* __restrict__ eW2, const float* __restrict__ eb2,
    const float* __restrict__ eW3, const float* __restrict__ eb3,
    const float* __restrict__ dx, const float* __restrict__ dadj,
    const float* __restrict__ dW1, const float* __restrict__ db1,
    const float* __restrict__ dW2, const float* __restrict__ db2,
    const float* __restrict__ dW3, const float* __restrict__ db3,
    const float* __restrict__ mlp_w, const float* __restrict__ mlp2_w,
    float* __restrict__ xe, float* __restrict__ de,
    float* __restrict__ x2b, float* __restrict__ yw) {
  __shared__ float As[64 * 65];
  __shared__ float Aa[64 * 65];
  __shared__ __align__(16) float C0[64 * 128];
  __shared__ __align__(16) float C1[64 * 128];
  int t = threadIdx.x;
  const float *src, *ad, *W1, *b1, *W2, *b2, *W3, *b3;
  float* outp;
  bool is_x = (blockIdx.x < 32);
  int g;
  if (is_x) {
    g = blockIdx.x;
    src = x + g * 4096; ad = adj + g * 4096;
    W1 = eW1; b1 = eb1; W2 = eW2; b2 = eb2; W3 = eW3; b3 = eb3;
    outp = xe + g * 2048;
  } else {
    g = blockIdx.x - 32;
    src = dx + g * 4096; ad = dadj + g * 4096;
    W1 = dW1; b1 = db1; W2 = dW2; b2 = db2; W3 = dW3; b3 = db3;
    outp = de + g * 2048;
  }
  {
    const float4* s4 = (const float4*)src;
    const float4* a4 = (const float4*)ad;
    for (int idx = t; idx < 1024; idx += 512) {
      int r = idx >> 4, c = (idx & 15) * 4;
      float4 v = s4[idx];
      As[r * 65 + c] = v.x; As[r * 65 + c + 1] = v.y;
      As[r * 65 + c + 2] = v.z; As[r * 65 + c + 3] = v.w;
      float4 w = a4[idx];
      Aa[r * 65 + c] = w.x; Aa[r * 65 + c + 1] = w.y;
      Aa[r * 65 + c + 2] = w.z; Aa[r * 65 + c + 3] = w.w;
    }
  }
  __syncthreads();
  mm64<64, 128, 512>(As, 65, W1, C1, nullptr, false, t);
  __syncthreads();
  mm64<64, 128, 512>(Aa, 65, C1, C0, b1, true, t);
  __syncthreads();
  mm64<128, 64, 512>(C0, 128, W2, C1, nullptr, false, t);
  __syncthreads();
  mm64<64, 64, 512>(Aa, 65, C1, C0, b2, true, t);
  __syncthreads();
  mm64<64, 32, 512>(C0, 64, W3, C1, nullptr, false, t);
  __syncthreads();
  mm64<64, 32, 512>(Aa, 65, C1, outp, b3, false, t);
  __syncthreads();
  if (is_x) {
    if (t < 64) {
      const float* r = outp + t * 32;
      float s = 0.f;
#pragma unroll
      for (int f = 0; f < 32; ++f) s += r[f] * r[f];
      x2b[g * 64 + t] = s;
    } else if (t < 96) {
      int f = t - 64;
      float s = 0.f, sb = 0.f;
      for (int n = 0; n < 64; ++n) {
        float v = outp[n * 32 + f];
        s += v * v;
        sb += v * mlp_w[n];
      }
      yw[g * 32 + f] = mlp2_w[g] * sb / (sqrtf(s) + 1e-12f);
    }
  }
}

// =====================================================================
// JAX threefry2x32, key = (0, 42)
// =====================================================================
__device__ __forceinline__ unsigned rotl32(unsigned v, int s) {
  return (v << s) | (v >> (32 - s));
}
__device__ __forceinline__ void threefry42(unsigned x0, unsigned x1,
                                           unsigned& o0, unsigned& o1) {
  const unsigned ks0 = 0u, ks1 = 42u, ks2 = 0x1BD11BDAu ^ 0u ^ 42u;
  unsigned ks[3] = {ks0, ks1, ks2};
  x0 += ks[0];
  x1 += ks[1];
  const int R[2][4] = {{13, 15, 26, 6}, {17, 29, 16, 24}};
#pragma unroll
  for (int r = 0; r < 5; ++r) {
    const int* rr = R[r & 1];
#pragma unroll
    for (int i = 0; i < 4; ++i) {
      x0 += x1;
      x1 = rotl32(x1, rr[i]);
      x1 ^= x0;
    }
    x0 += ks[(r + 1) % 3];
    x1 += ks[(r + 2) % 3] + (unsigned)(r + 1);
  }
  o0 = x0;
  o1 = x1;
}

// =====================================================================
__global__ __launch_bounds__(256) void attn_kernel(
    const float* __restrict__ de, const float* __restrict__ yw,
    const float* __restrict__ mlp_b, const float* __restrict__ mlp2_w,
    const float* __restrict__ mlp2_b, float* __restrict__ dsamp,
    float* __restrict__ y2, float* __restrict__ klpart) {
  int d = blockIdx.x, t = threadIdx.x;
  __shared__ float zs[32], dns[32], c0s[1];
  if (t < 32) {
    float zz = 0.f;
    for (int b = 0; b < 32; ++b) zz += yw[b * 32 + t];
    zs[t] = zz;
  } else if (t < 64) {
    int f = t - 32;
    float s = 0.f;
    for (int n = 0; n < 64; ++n) {
      float v = de[d * 2048 + n * 32 + f];
      s += v * v;
    }
    dns[f] = sqrtf(s) + 1e-12f;
  } else if (t == 64) {
    float sm2 = 0.f;
    for (int b = 0; b < 32; ++b) sm2 += mlp2_w[b];
    c0s[0] = mlp_b[0] * sm2 + mlp2_b[0];
  }
  __syncthreads();
  if (t < 64) {
    int m = t;
    const float* row = de + d * 2048 + m * 32;
    float logit = c0s[0], s2 = 0.f;
#pragma unroll 8
    for (int f = 0; f < 32; ++f) {
      float v = row[f];
      logit += (v / dns[f]) * zs[f];
      s2 += v * v;
    }
    float attn = 1.0f / (1.0f + expf(-logit));
    int e = d * 64 + m;
    unsigned o0, o1, bits;
    if (e < 960) {
      threefry42((unsigned)e, (unsigned)(960 + e), o0, o1);
      bits = o0;
    } else {
      threefry42((unsigned)(e - 960), (unsigned)e, o0, o1);
      bits = o1;
    }
    float u = __uint_as_float((bits >> 9) | 0x3f800000u) - 1.0f;
    u = fmaxf(u, 0.0f);
    float bern = (u < attn) ? 1.0f : 0.0f;
    float* dr = dsamp + d * 2048 + m * 32;
#pragma unroll 8
    for (int f = 0; f < 32; ++f) dr[f] = bern * row[f];
    y2[e] = bern * s2;
    float klt = attn * logf(2.0f * attn) + (1.0f - attn) * logf(2.0f * (1.0f - attn));
#pragma unroll
    for (int off = 32; off > 0; off >>= 1) klt += __shfl_down(klt, off, 64);
    if (m == 0) klpart[d] = klt;
  }
}

// =====================================================================
// Sinkhorn + gd. Grid 1920 = (b,d) x 2 halves; 256 thr = 4 waves = 4 lambdas.
// K lives in REGISTERS (packed bf16 deviation Kd = exp(-lam*M)-1; masked=-1):
// lane m holds row m (kr[32]) and col m (kc[32]). Iterations are pure VALU
// (readlane broadcast + shfl_xor sums) — zero LDS, zero barriers.
// After iterations each lane materializes its W row (bf16) into an LDS plane;
// the G-phase is then a pure GEMV with ds_read_b64 W loads and float4 dp.
// =====================================================================
__global__ __launch_bounds__(256) void sink_kernel(
    const float* __restrict__ xe, const float* __restrict__ ds,
    const float* __restrict__ x2g, const float* __restrict__ y2g,
    const int* __restrict__ num_node, const int* __restrict__ dict_nnode,
    const float* __restrict__ dp, float* __restrict__ gall) {
  // 4 W planes, 64 rows x 34 u32 (68 bf16, stride 136B: 8B-aligned, 2-way banks)
  __shared__ __align__(16) unsigned WdU[4 * 2176];        // 34816 B (aliases staging)
  __shared__ __align__(16) unsigned short Msb16[64 * 68]; // 8704 B, bf16 M
  __shared__ float w1s[64], w2s[64], x2s[64], y2s[64];
  __shared__ __align__(16) float Gred[4 * 8 * 4 * 4];     // [wave][k4][l][c]

  int t = threadIdx.x;
  int m = t & 63;
  int wv = t >> 6;
  int bd = blockIdx.x >> 1;
  int half = blockIdx.x & 1;
  int b = bd / 30;
  int d = bd - b * 30;

  // ---- stage xe/ds into stride-36 fp32 arrays aliased over WdU
  float* XEs = (float*)WdU;        // 64*36 floats = 9216 B
  float* DSs = XEs + 64 * 36;      // 9216 B more (18432 <= 34816)
  {
    const float4* xsrc = (const float4*)(xe + b * 2048);
    const float4* dsrc = (const float4*)(ds + d * 2048);
    for (int idx = t; idx < 512; idx += 256) {
      int r = idx >> 3, c4 = (idx & 7) * 4;
      *(float4*)&XEs[r * 36 + c4] = xsrc[idx];
      *(float4*)&DSs[r * 36 + c4] = dsrc[idx];
    }
  }
  if (t < 64) {
    int nn = num_node[b], dnn = dict_nnode[d];
    w1s[t] = (t < nn) ? 1.0f / (float)nn : 0.0f;
    w2s[t] = (t < dnn) ? 1.0f / (float)dnn : 0.0f;
    x2s[t] = x2g[b * 64 + t];
    y2s[t] = y2g[d * 64 + t];
  }
  __syncthreads();

  // ---- M-build: 4x4 register tile; thread (ti,tj) -> rows {ti+16r}, cols {tj+16c}
  {
    int ti = t >> 4, tj = t & 15;
    float acc[4][4];
#pragma unroll
    for (int r = 0; r < 4; ++r)
#pragma unroll
      for (int c = 0; c < 4; ++c) acc[r][c] = 0.f;
#pragma unroll
    for (int fc = 0; fc < 32; fc += 4) {
      float4 xv[4], dv[4];
#pragma unroll
      for (int r = 0; r < 4; ++r) xv[r] = *(const float4*)&XEs[(ti + 16 * r) * 36 + fc];
#pragma unroll
      for (int c = 0; c < 4; ++c) dv[c] = *(const float4*)&DSs[(tj + 16 * c) * 36 + fc];
#pragma unroll
      for (int r = 0; r < 4; ++r)
#pragma unroll
        for (int c = 0; c < 4; ++c)
          acc[r][c] += xv[r].x * dv[c].x + xv[r].y * dv[c].y +
                       xv[r].z * dv[c].z + xv[r].w * dv[c].w;
    }
#pragma unroll
    for (int r = 0; r < 4; ++r) {
      int i = ti + 16 * r;
#pragma unroll
      for (int c = 0; c < 4; ++c) {
        int j = tj + 16 * c;
        float mv = x2s[i] + y2s[j] - 2.0f * acc[r][c];
        Msb16[i * 68 + j] = (unsigned short)bf16_bits(mv);
      }
    }
  }
  __syncthreads();  // Msb16 complete; staging (WdU alias) dead

  // ---- K-build into registers: wave wv owns lambda = half*4+wv
  float lam = c_LAM[half * 4 + wv];
  unsigned kr[32], kc[32];
  {
    bool rv = (w1s[m] > 0.f);
    const uint2* mrow = (const uint2*)(Msb16 + m * 68);
#pragma unroll
    for (int jq = 0; jq < 16; ++jq) {
      uint2 mp = mrow[jq];
      int j0 = jq * 4;
      float m0 = bflo(mp.x), m1 = bfhi(mp.x), m2 = bflo(mp.y), m3 = bfhi(mp.y);
      float k0 = (rv && w2s[j0 + 0] > 0.f) ? (__expf(-lam * m0) - 1.0f) : -1.0f;
      float k1 = (rv && w2s[j0 + 1] > 0.f) ? (__expf(-lam * m1) - 1.0f) : -1.0f;
      float k2 = (rv && w2s[j0 + 2] > 0.f) ? (__expf(-lam * m2) - 1.0f) : -1.0f;
      float k3 = (rv && w2s[j0 + 3] > 0.f) ? (__expf(-lam * m3) - 1.0f) : -1.0f;
      kr[jq * 2 + 0] = bf16_bits(k0) | (bf16_bits(k1) << 16);
      kr[jq * 2 + 1] = bf16_bits(k2) | (bf16_bits(k3) << 16);
    }
    bool cv = (w2s[m] > 0.f);
#pragma unroll
    for (int iq = 0; iq < 32; ++iq) {
      float mA = bf16_val(Msb16[(2 * iq) * 68 + m]);
      float mB = bf16_val(Msb16[(2 * iq + 1) * 68 + m]);
      float kA = (cv && w1s[2 * iq] > 0.f) ? (__expf(-lam * mA) - 1.0f) : -1.0f;
      float kB = (cv && w1s[2 * iq + 1] > 0.f) ? (__expf(-lam * mB) - 1.0f) : -1.0f;
      kc[iq] = bf16_bits(kA) | (bf16_bits(kB) << 16);
    }
  }

  // ---- Sinkhorn iterations: registers only
  float w1m = w1s[m], w2m = w2s[m];
  float u = 1.0f, v = 0.0f;
  for (int it = 0; it < 10; ++it) {
    float Su = u;
#pragma unroll
    for (int off = 1; off < 64; off <<= 1) Su += __shfl_xor(Su, off, 64);
    float tv = 0.f;
#pragma unroll
    for (int iq = 0; iq < 32; ++iq) {
      tv = fmaf(bflo(kc[iq]), lane_bcast(u, 2 * iq), tv);
      tv = fmaf(bfhi(kc[iq]), lane_bcast(u, 2 * iq + 1), tv);
    }
    v = w2m / (Su + tv + 1e-6f);
    float Sv = v;
#pragma unroll
    for (int off = 1; off < 64; off <<= 1) Sv += __shfl_xor(Sv, off, 64);
    float tu = 0.f;
#pragma unroll
    for (int jq = 0; jq < 32; ++jq) {
      tu = fmaf(bflo(kr[jq]), lane_bcast(v, 2 * jq), tu);
      tu = fmaf(bfhi(kr[jq]), lane_bcast(v, 2 * jq + 1), tu);
    }
    u = w1m / (Sv + tu + 1e-6f);
  }

  // ---- row min/max + W row materialization (lane m -> plane wv row m)
  {
    float mx = -3.402823466e38f, mn = 3.402823466e38f;
#pragma unroll
    for (int jq = 0; jq < 32; ++jq) {
      float uv0 = u * lane_bcast(v, 2 * jq);
      float uv1 = u * lane_bcast(v, 2 * jq + 1);
      float g0 = fmaf(bflo(kr[jq]), uv0, uv0);
      float g1 = fmaf(bfhi(kr[jq]), uv1, uv1);
      mx = fmaxf(mx, fmaxf(g0, g1));
      mn = fminf(mn, fminf(g0, g1));
    }
    float rm = mn, ri = 1.0f / (mx - mn + 1e-6f);
    const uint2* mrow = (const uint2*)(Msb16 + m * 68);
    uint2* wrow = (uint2*)(WdU + wv * 2176 + m * 34);
#pragma unroll
    for (int jq = 0; jq < 16; ++jq) {
      uint2 mp = mrow[jq];
      int j0 = jq * 4;
      float mvv0 = bflo(mp.x), mvv1 = bfhi(mp.x), mvv2 = bflo(mp.y), mvv3 = bfhi(mp.y);
      unsigned kp0 = kr[jq * 2], kp1 = kr[jq * 2 + 1];
      float uvA = u * lane_bcast(v, j0 + 0);
      float uvB = u * lane_bcast(v, j0 + 1);
      float uvC = u * lane_bcast(v, j0 + 2);
      float uvD = u * lane_bcast(v, j0 + 3);
      float gA = fmaf(bflo(kp0), uvA, uvA);
      float gB = fmaf(bfhi(kp0), uvB, uvB);
      float gC = fmaf(bflo(kp1), uvC, uvC);
      float gD = fmaf(bfhi(kp1), uvD, uvD);
      float wA = (gA - rm) * ri * mvv0;
      float wB = (gB - rm) * ri * mvv1;
      float wC = (gC - rm) * ri * mvv2;
      float wD = (gD - rm) * ri * mvv3;
      uint2 o;
      o.x = bf16_bits(wA) | (bf16_bits(wB) << 16);
      o.y = bf16_bits(wC) | (bf16_bits(wD) << 16);
      wrow[jq] = o;
    }
  }
  __syncthreads();

  // ---- G-phase: pure GEMV. thread (gq = t>>3, k4 = t&7) -> rows 2gq,2gq+1
  int gq = t >> 3, k4 = t & 7;
  const float4* dp4 = (const float4*)dp;
  float4 acc4[4];
#pragma unroll
  for (int l = 0; l < 4; ++l) acc4[l] = make_float4(0.f, 0.f, 0.f, 0.f);

#pragma unroll
  for (int ii = 0; ii < 2; ++ii) {
    int i = gq * 2 + ii;
    const uint2* wr0 = (const uint2*)(WdU + 0 * 2176 + i * 34);
    const uint2* wr1 = (const uint2*)(WdU + 1 * 2176 + i * 34);
    const uint2* wr2 = (const uint2*)(WdU + 2 * 2176 + i * 34);
    const uint2* wr3 = (const uint2*)(WdU + 3 * 2176 + i * 34);
    for (int jq = 0; jq < 16; ++jq) {
      int p = i * 64 + jq * 4;
      float4 d0 = dp4[(p + 0) * 8 + k4];
      float4 d1 = dp4[(p + 1) * 8 + k4];
      float4 d2 = dp4[(p + 2) * 8 + k4];
      float4 d3 = dp4[(p + 3) * 8 + k4];
      uint2 wp[4] = {wr0[jq], wr1[jq], wr2[jq], wr3[jq]};
#pragma unroll
      for (int l = 0; l < 4; ++l) {
        float a0 = bflo(wp[l].x), a1 = bfhi(wp[l].x);
        float a2 = bflo(wp[l].y), a3 = bfhi(wp[l].y);
        acc4[l].x += a0 * d0.x + a1 * d1.x + a2 * d2.x + a3 * d3.x;
        acc4[l].y += a0 * d0.y + a1 * d1.y + a2 * d2.y + a3 * d3.y;
        acc4[l].z += a0 * d0.z + a1 * d1.z + a2 * d2.z + a3 * d3.z;
        acc4[l].w += a0 * d0.w + a1 * d1.w + a2 * d2.w + a3 * d3.w;
      }
    }
  }
  // in-wave reduce over the 8 gq-subgroups (lane stride 8)
#pragma unroll
  for (int off = 32; off >= 8; off >>= 1) {
#pragma unroll
    for (int l = 0; l < 4; ++l) {
      acc4[l].x += __shfl_down(acc4[l].x, off, 64);
      acc4[l].y += __shfl_down(acc4[l].y, off, 64);
      acc4[l].z += __shfl_down(acc4[l].z, off, 64);
      acc4[l].w += __shfl_down(acc4[l].w, off, 64);
    }
  }
  if ((t & 63) < 8) {
#pragma unroll
    for (int l = 0; l < 4; ++l)
      *(float4*)&Gred[((wv * 8 + k4) * 4 + l) * 4] = acc4[l];
  }
  __syncthreads();
  if (t < 128) {
    int l = t >> 5, k = t & 31;
    int kq = k >> 2, kcmp = k & 3;
    float s = 0.f;
#pragma unroll
    for (int w = 0; w < 4; ++w) s += Gred[((w * 8 + kq) * 4 + l) * 4 + kcmp];
    int lg = half * 4 + l;
    gall[(size_t)((lg * 32 + b) * 30 + d) * 32 + k] = s;
  }
}

// =====================================================================
__global__ __launch_bounds__(256) void final_kernel(
    const float* __restrict__ gall, const float* __restrict__ wl,
    const float* __restrict__ fc1w, const float* __restrict__ fc1b,
    const float* __restrict__ fc2w, const float* __restrict__ fc2b,
    const float* __restrict__ klpart, float* __restrict__ out) {
  int b = blockIdx.x, t = threadIdx.x;
  __shared__ __align__(16) float4 embedL4[240];
  __shared__ float sred[32];
  __shared__ float coeff[8];
  __shared__ float hL[64];
  float part[8] = {0, 0, 0, 0, 0, 0, 0, 0};
  for (int j = t; j < 960; j += 256) {
    float w = wl[j];
#pragma unroll
    for (int l = 0; l < 8; ++l) part[l] += gall[l * 30720 + b * 960 + j] * w;
  }
#pragma unroll
  for (int off = 32; off > 0; off >>= 1) {
#pragma unroll
    for (int l = 0; l < 8; ++l) part[l] += __shfl_down(part[l], off, 64);
  }
  int wv = t >> 6, lane = t & 63;
  if (lane == 0) {
#pragma unroll
    for (int l = 0; l < 8; ++l) sred[l * 4 + wv] = part[l];
  }
  __syncthreads();
  if (t == 0) {
    float s[8], mx = -3.402823466e38f;
#pragma unroll
    for (int l = 0; l < 8; ++l) {
      s[l] = sred[l * 4] + sred[l * 4 + 1] + sred[l * 4 + 2] + sred[l * 4 + 3];
      mx = fmaxf(mx, s[l]);
    }
    float se = 0.f;
#pragma unroll
    for (int l = 0; l < 8; ++l) {
      s[l] = expf(s[l] - mx);
      se += s[l];
    }
#pragma unroll
    for (int l = 0; l < 8; ++l) coeff[l] = s[l] / se;
  }
  __syncthreads();
  for (int j = t; j < 960; j += 256) {
    float e = 0.f;
#pragma unroll
    for (int l = 0; l < 8; ++l) e += gall[l * 30720 + b * 960 + j] * coeff[l];
    ((float*)embedL4)[j] = e;
  }
  __syncthreads();
  {
    int o = t >> 2, l4 = t & 3;
    const float4* w4 = (const float4*)fc1w;
    float hp = 0.f;
#pragma unroll 4
    for (int k = 0; k < 60; ++k) {
      int jf = l4 + 4 * k;
      float4 wv4 = w4[o * 240 + jf];
      float4 ev = embedL4[jf];
      hp += wv4.x * ev.x + wv4.y * ev.y + wv4.z * ev.z + wv4.w * ev.w;
    }
    hp += __shfl_down(hp, 2, 64);
    hp += __shfl_down(hp, 1, 64);
    if (l4 == 0) hL[o] = hp + fc1b[o];
  }
  __syncthreads();
  if (t < 3) {
    float o = fc2b[t];
#pragma unroll
    for (int j = 0; j < 64; ++j) o += hL[j] * fc2w[t * 64 + j];
    out[b * 3 + t] = o;
  }
  if (b == 0 && t == 4) {
    float kl = 0.f;
    for (int dd = 0; dd < 30; ++dd) kl += klpart[dd];
    out[96] = kl;
  }
}

// =====================================================================
extern "C" void kernel_launch(void* const* d_in, const int* in_sizes, int n_in,
                              void* d_out, int out_size, void* d_ws,
                              size_t ws_size, hipStream_t stream) {
  (void)in_sizes; (void)n_in; (void)out_size; (void)ws_size;
  const float* x = (const float*)d_in[0];
  const float* adj = (const float*)d_in[1];
  const int* num_node = (const int*)d_in[2];
  const float* dict_feat = (const float*)d_in[3];
  const float* dict_adj = (const float*)d_in[4];
  const int* dict_nnode = (const int*)d_in[5];
  const float* eW1 = (const float*)d_in[6];
  const float* eb1 = (const float*)d_in[7];
  const float* eW2 = (const float*)d_in[8];
  const float* eb2 = (const float*)d_in[9];
  const float* eW3 = (const float*)d_in[10];
  const float* eb3 = (const float*)d_in[11];
  const float* dW1 = (const float*)d_in[12];
  const float* db1 = (const float*)d_in[13];
  const float* dW2 = (const float*)d_in[14];
  const float* db2 = (const float*)d_in[15];
  const float* dW3 = (const float*)d_in[16];
  const float* db3 = (const float*)d_in[17];
  const float* mlp_w = (const float*)d_in[18];
  const float* mlp_b = (const float*)d_in[19];
  const float* mlp2_w = (const float*)d_in[20];
  const float* mlp2_b = (const float*)d_in[21];
  const float* dist_para = (const float*)d_in[22];
  const float* weight_lamda = (const float*)d_in[23];
  const float* fc1_w = (const float*)d_in[24];
  const float* fc1_b = (const float*)d_in[25];
  const float* fc2_w = (const float*)d_in[26];
  const float* fc2_b = (const float*)d_in[27];

  float* ws = (float*)d_ws;
  float* xe = ws + OFF_XE;
  float* de = ws + OFF_DE;
  float* dsb = ws + OFF_DS;
  float* x2b = ws + OFF_X2;
  float* y2b = ws + OFF_Y2;
  float* ywb = ws + OFF_YW;
  float* klb = ws + OFF_KL;
  float* gall = ws + OFF_GALL;

  gcn_kernel<<<62, 512, 0, stream>>>(x, adj, eW1, eb1, eW2, eb2, eW3, eb3,
                                     dict_feat, dict_adj, dW1, db1, dW2, db2,
                                     dW3, db3, mlp_w, mlp2_w, xe, de, x2b, ywb);
  attn_kernel<<<30, 256, 0, stream>>>(de, ywb, mlp_b, mlp2_w, mlp2_b, dsb,
                                      y2b, klb);
  sink_kernel<<<1920, 256, 0, stream>>>(xe, dsb, x2b, y2b, num_node,
                                        dict_nnode, dist_para, gall);
  final_kernel<<<32, 256, 0, stream>>>(gall, weight_lamda, fc1_w, fc1_b, fc2_w,
                                       fc2_b, klb, (float*)d_out);
}